// Round 1
// baseline (459.468 us; speedup 1.0000x reference)
//
#include <hip/hip_runtime.h>
#include <math.h>

#define CK __restrict__

constexpr int CH = 256;
constexpr int HW = 1024;   // 32*32

// ---------------------------------------------------------------------------
// GEMM: Y[b][o][n] = sum_c W[o*256+c] * X[b][c][n] + bias[o]
// grid (16 n-tiles, 4 o-tiles, 4 b), block 256, 64x64 tile, 4x4 micro.
// ---------------------------------------------------------------------------
__global__ __launch_bounds__(256) void gemm256(const float* CK X, const float* CK W,
                                               const float* CK bias, float* CK Y) {
    __shared__ float Ws[16][68];   // [k][m], pitch 68 keeps float4 rows 16B-aligned
    __shared__ float Xs[16][64];   // [k][n]
    const int b  = blockIdx.z;
    const int m0 = blockIdx.y * 64, n0 = blockIdx.x * 64;
    const int t  = threadIdx.x;
    const int tx = t & 15, ty = t >> 4;
    const float* Xb = X + b * (CH * HW);
    float acc[4][4] = {};
    for (int k0 = 0; k0 < 256; k0 += 16) {
        {
            int o_l = t >> 2, c_l = (t & 3) << 2;
            const float4 w4 = *(const float4*)(W + (m0 + o_l) * 256 + k0 + c_l);
            Ws[c_l + 0][o_l] = w4.x; Ws[c_l + 1][o_l] = w4.y;
            Ws[c_l + 2][o_l] = w4.z; Ws[c_l + 3][o_l] = w4.w;
        }
        {
            int c_l = t >> 4, n_l = (t & 15) << 2;
            *(float4*)&Xs[c_l][n_l] = *(const float4*)(Xb + (k0 + c_l) * HW + n0 + n_l);
        }
        __syncthreads();
#pragma unroll
        for (int kk = 0; kk < 16; kk++) {
            float4 a4 = *(const float4*)&Ws[kk][ty << 2];
            float4 b4 = *(const float4*)&Xs[kk][tx << 2];
            float av[4] = {a4.x, a4.y, a4.z, a4.w};
            float bv[4] = {b4.x, b4.y, b4.z, b4.w};
#pragma unroll
            for (int i = 0; i < 4; i++)
#pragma unroll
                for (int j = 0; j < 4; j++) acc[i][j] += av[i] * bv[j];
        }
        __syncthreads();
    }
#pragma unroll
    for (int i = 0; i < 4; i++) {
        float bs = bias[m0 + (ty << 2) + i];
        float4 r;
        r.x = acc[i][0] + bs; r.y = acc[i][1] + bs;
        r.z = acc[i][2] + bs; r.w = acc[i][3] + bs;
        *(float4*)(Y + b * (CH * HW) + (m0 + (ty << 2) + i) * HW + n0 + (tx << 2)) = r;
    }
}

// ---------------------------------------------------------------------------
// Depthwise 5x5 conv, pad 2.  One block per (bg*64+ch); 256 thr x 4 pixels.
// q viewed as (16, 64, 32, 32) flat == (4, 256, 32, 32).
// ---------------------------------------------------------------------------
__global__ __launch_bounds__(256) void dwconv(const float* CK q, const float* CK wdw,
                                              const float* CK bdw, float* CK off) {
    const int bx = blockIdx.x;          // = bg*64 + ch
    const int ch = bx & 63;
    const float* qb = q + bx * HW;
    float w[25];
#pragma unroll
    for (int i = 0; i < 25; i++) w[i] = wdw[ch * 25 + i];
    const float bb = bdw[ch];
    const int t = threadIdx.x;
#pragma unroll
    for (int p = 0; p < 4; p++) {
        int hw = p * 256 + t;
        int ii = hw >> 5, jj = hw & 31;
        float s = bb;
#pragma unroll
        for (int ky = 0; ky < 5; ky++) {
            int y = ii + ky - 2;
            if (y < 0 || y > 31) continue;
#pragma unroll
            for (int kx = 0; kx < 5; kx++) {
                int x = jj + kx - 2;
                if (x < 0 || x > 31) continue;
                s += qb[y * 32 + x] * w[ky * 5 + kx];
            }
        }
        off[bx * HW + hw] = s;
    }
}

// ---------------------------------------------------------------------------
// LayerNorm(ch=64) + exact GELU + 2-ch projection + tanh + ref -> pos.
// Thread per (bg, hw); 16384 threads. Also emits outputs 1 (pos) and 2 (ref).
// ---------------------------------------------------------------------------
__global__ __launch_bounds__(256) void ln_pos(const float* CK off, const float* CK ln_g,
                                              const float* CK ln_b, const float* CK wpj,
                                              float* CK pos_ws, float* CK out_pos,
                                              float* CK out_ref) {
    const int gid = blockIdx.x * 256 + threadIdx.x;
    const int bg = gid >> 10, hw = gid & 1023;
    const float* ob = off + bg * 64 * HW + hw;
    float s1 = 0.f;
#pragma unroll
    for (int c = 0; c < 64; c++) s1 += ob[c * HW];
    const float mean = s1 * 0.015625f;
    float s2 = 0.f;
#pragma unroll
    for (int c = 0; c < 64; c++) { float d = ob[c * HW] - mean; s2 += d * d; }
    const float rs = rsqrtf(s2 * 0.015625f + 1e-5f);
    float p0 = 0.f, p1 = 0.f;
#pragma unroll
    for (int c = 0; c < 64; c++) {
        float vv = (ob[c * HW] - mean) * rs * ln_g[c] + ln_b[c];
        float gl = 0.5f * vv * (1.f + erff(vv * 0.70710678118654752f));
        p0 += gl * wpj[c];
        p1 += gl * wpj[64 + c];
    }
    const int i = hw >> 5, j = hw & 31;
    const float r0 = (j + 0.5f) * 0.0625f - 1.f;   // ref ch0 <- column (meshgrid-xy quirk)
    const float r1 = (i + 0.5f) * 0.0625f - 1.f;   // ref ch1 <- row
    const float pos0 = tanhf(p0) * 0.0625f + r0;   // tanh * (1/32) * ORF(=2)
    const float pos1 = tanhf(p1) * 0.0625f + r1;
    pos_ws[gid * 2] = pos0;  pos_ws[gid * 2 + 1] = pos1;
    out_pos[gid * 2] = pos0; out_pos[gid * 2 + 1] = pos1;
    out_ref[gid * 2] = r0;   out_ref[gid * 2 + 1] = r1;
}

// ---------------------------------------------------------------------------
// Bilinear sample of x (as (16,64,32,32)) at pos -> xs (as (4,256,1024)).
// gx from pos ch1, gy from pos ch0 (reference's [..., ::-1] flip).
// ---------------------------------------------------------------------------
__global__ __launch_bounds__(256) void sample_xs(const float* CK x, const float* CK pos_ws,
                                                 float* CK xs) {
    const int gid = blockIdx.x * 256 + threadIdx.x;
    const int bg = gid >> 10, n = gid & 1023;
    const float p0 = pos_ws[gid * 2], p1 = pos_ws[gid * 2 + 1];
    const float gx = (p1 + 1.f) * 15.5f, gy = (p0 + 1.f) * 15.5f;   // 0.5*(32-1)
    const float x0f = floorf(gx), y0f = floorf(gy);
    const float wx1 = gx - x0f, wx0 = 1.f - wx1, wy1 = gy - y0f, wy0 = 1.f - wy1;
    const bool vx0 = (x0f >= 0.f) && (x0f <= 31.f);
    const bool vx1 = (x0f >= -1.f) && (x0f <= 30.f);
    const bool vy0 = (y0f >= 0.f) && (y0f <= 31.f);
    const bool vy1 = (y0f >= -1.f) && (y0f <= 30.f);
    const int xi0 = (int)fminf(fmaxf(x0f, 0.f), 31.f);
    const int xi1 = (int)fminf(fmaxf(x0f + 1.f, 0.f), 31.f);
    const int yi0 = (int)fminf(fmaxf(y0f, 0.f), 31.f);
    const int yi1 = (int)fminf(fmaxf(y0f + 1.f, 0.f), 31.f);
    const float w00 = (vy0 && vx0) ? wy0 * wx0 : 0.f;
    const float w01 = (vy0 && vx1) ? wy0 * wx1 : 0.f;
    const float w10 = (vy1 && vx0) ? wy1 * wx0 : 0.f;
    const float w11 = (vy1 && vx1) ? wy1 * wx1 : 0.f;
    const int o00 = yi0 * 32 + xi0, o01 = yi0 * 32 + xi1;
    const int o10 = yi1 * 32 + xi0, o11 = yi1 * 32 + xi1;
    const float* xb = x + bg * 64 * HW;
    float* xo = xs + bg * 64 * HW + n;
#pragma unroll
    for (int c = 0; c < 64; c++) {
        const float* p = xb + c * HW;
        xo[c * HW] = w00 * p[o00] + w01 * p[o01] + w10 * p[o10] + w11 * p[o11];
    }
}

// ---------------------------------------------------------------------------
// Flash attention with RPE bilinear bias.
// grid (8 m-tiles, 32 bh), block 256 = 64 m-slots x 4 n-groups; thread owns 2 m.
// k/v chunks (32c x 128n) fp32 in LDS; rpe plane (63x63) in LDS; online softmax
// per (thread, m); 4 n-group partials merged via LDS at the end.
// ---------------------------------------------------------------------------
__global__ __launch_bounds__(256, 1) void attn_kernel(const float* CK q, const float* CK k,
                                                      const float* CK v, const float* CK pos_ws,
                                                      const float* CK rpe, float* CK out) {
    __shared__ float rpe_s[3969];
    __shared__ float ks[32][128];
    __shared__ float vs[32][128];
    __shared__ float poss[256];              // [n_local][2]
    __shared__ float red[2][64][4][2];       // [h][mi][gq][{max,sum}]
    __shared__ float outf[128 * 33];         // [m_local][c], pitch 33
    const int bh = blockIdx.y;
    const int m0 = blockIdx.x * 128;
    const int b = bh >> 3, nh = bh & 7, bg = bh >> 1;
    const int t = threadIdx.x, mi = t & 63, gq = t >> 6;

    const float* rp = rpe + nh * 3969;
    for (int i = t; i < 3969; i += 256) rpe_s[i] = rp[i];
    for (int i = t; i < 128 * 33; i += 256) outf[i] = 0.f;

    const float* qb = q + (b * 256 + nh * 32) * HW + m0 + mi;
    float qr[2][32];
#pragma unroll
    for (int c = 0; c < 32; c++) { qr[0][c] = qb[c * HW]; qr[1][c] = qb[c * HW + 64]; }
    float qg0[2], qg1[2];
#pragma unroll
    for (int h = 0; h < 2; h++) {
        int m = m0 + mi + h * 64;
        qg0[h] = ((m & 31) + 0.5f) * 0.0625f - 1.f;
        qg1[h] = ((m >> 5) + 0.5f) * 0.0625f - 1.f;
    }
    float oacc[2][32] = {};
    float rmax[2] = {-1e30f, -1e30f}, rsum[2] = {0.f, 0.f};
    const float* kb = k + (b * 256 + nh * 32) * HW;
    const float* vb = v + (b * 256 + nh * 32) * HW;
    const float* pb = pos_ws + bg * 2048;

    for (int nc = 0; nc < 8; nc++) {
        __syncthreads();
#pragma unroll
        for (int l = 0; l < 4; l++) {
            int f4 = t + l * 256;                       // 0..1023
            int c_l = f4 >> 5, n_l = (f4 & 31) << 2;
            *(float4*)&ks[c_l][n_l] = *(const float4*)(kb + c_l * HW + nc * 128 + n_l);
            *(float4*)&vs[c_l][n_l] = *(const float4*)(vb + c_l * HW + nc * 128 + n_l);
        }
        poss[t] = pb[nc * 256 + t];
        __syncthreads();

        for (int ng = 0; ng < 8; ng++) {
            const int nl0 = gq * 32 + ng * 4;
            float dot[2][4] = {};
#pragma unroll
            for (int c = 0; c < 32; c++) {
                float4 k4 = *(const float4*)&ks[c][nl0];
                dot[0][0] += qr[0][c] * k4.x; dot[0][1] += qr[0][c] * k4.y;
                dot[0][2] += qr[0][c] * k4.z; dot[0][3] += qr[0][c] * k4.w;
                dot[1][0] += qr[1][c] * k4.x; dot[1][1] += qr[1][c] * k4.y;
                dot[1][2] += qr[1][c] * k4.z; dot[1][3] += qr[1][c] * k4.w;
            }
            float s[2][4];
#pragma unroll
            for (int j = 0; j < 4; j++) {
                const float pp0 = poss[(nl0 + j) * 2], pp1 = poss[(nl0 + j) * 2 + 1];
#pragma unroll
                for (int h = 0; h < 2; h++) {
                    float d0 = (qg0[h] - pp0) * 0.5f, d1 = (qg1[h] - pp1) * 0.5f;
                    float gx = (d1 + 1.f) * 31.f, gy = (d0 + 1.f) * 31.f;  // 0.5*(63-1)
                    float x0f = floorf(gx), y0f = floorf(gy);
                    float wx1 = gx - x0f, wx0 = 1.f - wx1;
                    float wy1 = gy - y0f, wy0 = 1.f - wy1;
                    bool vx0 = (x0f >= 0.f) && (x0f <= 62.f);
                    bool vx1 = (x0f >= -1.f) && (x0f <= 61.f);
                    bool vy0 = (y0f >= 0.f) && (y0f <= 62.f);
                    bool vy1 = (y0f >= -1.f) && (y0f <= 61.f);
                    int xi0 = (int)fminf(fmaxf(x0f, 0.f), 62.f);
                    int xi1 = (int)fminf(fmaxf(x0f + 1.f, 0.f), 62.f);
                    int yi0 = (int)fminf(fmaxf(y0f, 0.f), 62.f);
                    int yi1 = (int)fminf(fmaxf(y0f + 1.f, 0.f), 62.f);
                    float w00 = (vy0 && vx0) ? wy0 * wx0 : 0.f;
                    float w01 = (vy0 && vx1) ? wy0 * wx1 : 0.f;
                    float w10 = (vy1 && vx0) ? wy1 * wx0 : 0.f;
                    float w11 = (vy1 && vx1) ? wy1 * wx1 : 0.f;
                    float bias = w00 * rpe_s[yi0 * 63 + xi0] + w01 * rpe_s[yi0 * 63 + xi1]
                               + w10 * rpe_s[yi1 * 63 + xi0] + w11 * rpe_s[yi1 * 63 + xi1];
                    s[h][j] = dot[h][j] * 0.17677669529663687f + bias;
                }
            }
            float wgt[2][4];
#pragma unroll
            for (int h = 0; h < 2; h++) {
                float gm = fmaxf(fmaxf(s[h][0], s[h][1]), fmaxf(s[h][2], s[h][3]));
                if (gm > rmax[h]) {
                    float corr = __expf(rmax[h] - gm);
                    rsum[h] *= corr;
#pragma unroll
                    for (int c = 0; c < 32; c++) oacc[h][c] *= corr;
                    rmax[h] = gm;
                }
#pragma unroll
                for (int j = 0; j < 4; j++) wgt[h][j] = __expf(s[h][j] - rmax[h]);
                rsum[h] += wgt[h][0] + wgt[h][1] + wgt[h][2] + wgt[h][3];
            }
#pragma unroll
            for (int c = 0; c < 32; c++) {
                float4 v4 = *(const float4*)&vs[c][nl0];
                oacc[0][c] += wgt[0][0] * v4.x + wgt[0][1] * v4.y + wgt[0][2] * v4.z + wgt[0][3] * v4.w;
                oacc[1][c] += wgt[1][0] * v4.x + wgt[1][1] * v4.y + wgt[1][2] * v4.z + wgt[1][3] * v4.w;
            }
        }
    }

    __syncthreads();
#pragma unroll
    for (int h = 0; h < 2; h++) { red[h][mi][gq][0] = rmax[h]; red[h][mi][gq][1] = rsum[h]; }
    __syncthreads();
#pragma unroll
    for (int h = 0; h < 2; h++) {
        float M = red[h][mi][0][0];
#pragma unroll
        for (int g2 = 1; g2 < 4; g2++) M = fmaxf(M, red[h][mi][g2][0]);
        float S = 0.f;
#pragma unroll
        for (int g2 = 0; g2 < 4; g2++) S += red[h][mi][g2][1] * __expf(red[h][mi][g2][0] - M);
        float f = __expf(rmax[h] - M) / S;
#pragma unroll
        for (int c = 0; c < 32; c++) atomicAdd(&outf[(h * 64 + mi) * 33 + c], oacc[h][c] * f);
    }
    __syncthreads();
    {
        float* ob = out + (b * 256 + nh * 32) * HW + m0;
        int ml = t & 63, cq = t >> 6;
#pragma unroll
        for (int cc = 0; cc < 8; cc++) {
            int c = cq * 8 + cc;
            ob[c * HW + ml]      = outf[ml * 33 + c];
            ob[c * HW + 64 + ml] = outf[(64 + ml) * 33 + c];
        }
    }
}

// ---------------------------------------------------------------------------
extern "C" void kernel_launch(void* const* d_in, const int* in_sizes, int n_in,
                              void* d_out, int out_size, void* d_ws, size_t ws_size,
                              hipStream_t stream) {
    (void)in_sizes; (void)n_in; (void)out_size; (void)ws_size;
    const float* x   = (const float*)d_in[0];
    const float* wq  = (const float*)d_in[1];
    const float* bq  = (const float*)d_in[2];
    const float* wdw = (const float*)d_in[3];
    const float* bdw = (const float*)d_in[4];
    const float* lng = (const float*)d_in[5];
    const float* lnb = (const float*)d_in[6];
    const float* wpj = (const float*)d_in[7];
    const float* wk  = (const float*)d_in[8];
    const float* bk  = (const float*)d_in[9];
    const float* wv  = (const float*)d_in[10];
    const float* bv  = (const float*)d_in[11];
    const float* wo  = (const float*)d_in[12];
    const float* bo  = (const float*)d_in[13];
    const float* rpe = (const float*)d_in[14];
    float* outp = (float*)d_out;
    float* ws = (float*)d_ws;

    float* q_ws    = ws;                 // 1M floats
    float* off_ws  = ws + (1 << 20);     // 1M floats (reused as attention output)
    float* xs_ws   = ws + (2 << 20);     // 1M floats
    float* k_ws    = ws + (3 << 20);     // 1M floats
    float* v_ws    = ws + (4 << 20);     // 1M floats
    float* pos_ws  = ws + (5 << 20);     // 32K floats
    float* attno_ws = off_ws;

    dim3 gg(16, 4, 4);
    gemm256<<<gg, 256, 0, stream>>>(x, wq, bq, q_ws);
    dwconv<<<1024, 256, 0, stream>>>(q_ws, wdw, bdw, off_ws);
    ln_pos<<<64, 256, 0, stream>>>(off_ws, lng, lnb, wpj, pos_ws,
                                   outp + (1 << 20), outp + (1 << 20) + 32768);
    sample_xs<<<64, 256, 0, stream>>>(x, pos_ws, xs_ws);
    gemm256<<<gg, 256, 0, stream>>>(xs_ws, wk, bk, k_ws);
    gemm256<<<gg, 256, 0, stream>>>(xs_ws, wv, bv, v_ws);
    attn_kernel<<<dim3(8, 32), 256, 0, stream>>>(q_ws, k_ws, v_ws, pos_ws, rpe, attno_ws);
    gemm256<<<gg, 256, 0, stream>>>(attno_ws, wo, bo, outp);
}

// Round 2
// 381.275 us; speedup vs baseline: 1.2051x; 1.2051x over previous
//
#include <hip/hip_runtime.h>
#include <math.h>

#define CK __restrict__

constexpr int CH = 256;
constexpr int HW = 1024;   // 32*32

// ---------------------------------------------------------------------------
// GEMM: Y[b][o][n] = sum_c W[o*256+c] * X[b][c][n] + bias[o]
// Tile 64(m) x 32(n), 256 threads, micro 2x4.  grid (32 n-tiles, 4 m-tiles,
// 4*b or 8 for fused dual-weight mode: z&3 = b, z>>2 selects (W,bias,Y) set).
// 512-1024 blocks -> 2-4 blocks/CU (vs 1 before): latency hiding.
// ---------------------------------------------------------------------------
__global__ __launch_bounds__(256) void gemm64x32(const float* CK X,
                                                 const float* CK W0, const float* CK b0, float* CK Y0,
                                                 const float* CK W1, const float* CK b1, float* CK Y1) {
    __shared__ float Ws[16][68];   // [k][m], pitch 68 (272B rows, 16B aligned)
    __shared__ float Xs[16][32];   // [k][n]
    const int b   = blockIdx.z & 3;
    const int sel = blockIdx.z >> 2;
    const float* W    = sel ? W1 : W0;
    const float* bias = sel ? b1 : b0;
    float* Y          = sel ? Y1 : Y0;
    const int m0 = blockIdx.y * 64, n0 = blockIdx.x * 32;
    const int t  = threadIdx.x;
    const int tx = t & 7, ty = t >> 3;          // tx: 4-col group, ty: 2-row group
    const float* Xb = X + b * (CH * HW);
    float acc[2][4] = {};
    for (int k0 = 0; k0 < 256; k0 += 16) {
        {
            int o_l = t >> 2, c_l = (t & 3) << 2;
            const float4 w4 = *(const float4*)(W + (m0 + o_l) * 256 + k0 + c_l);
            Ws[c_l + 0][o_l] = w4.x; Ws[c_l + 1][o_l] = w4.y;
            Ws[c_l + 2][o_l] = w4.z; Ws[c_l + 3][o_l] = w4.w;
        }
        if (t < 128) {
            int c_l = t >> 3, n_l = (t & 7) << 2;
            *(float4*)&Xs[c_l][n_l] = *(const float4*)(Xb + (k0 + c_l) * HW + n0 + n_l);
        }
        __syncthreads();
#pragma unroll
        for (int kk = 0; kk < 16; kk++) {
            float2 a2 = *(const float2*)&Ws[kk][ty << 1];
            float4 b4 = *(const float4*)&Xs[kk][tx << 2];
            acc[0][0] += a2.x * b4.x; acc[0][1] += a2.x * b4.y;
            acc[0][2] += a2.x * b4.z; acc[0][3] += a2.x * b4.w;
            acc[1][0] += a2.y * b4.x; acc[1][1] += a2.y * b4.y;
            acc[1][2] += a2.y * b4.z; acc[1][3] += a2.y * b4.w;
        }
        __syncthreads();
    }
#pragma unroll
    for (int i = 0; i < 2; i++) {
        float bs = bias[m0 + (ty << 1) + i];
        float4 r;
        r.x = acc[i][0] + bs; r.y = acc[i][1] + bs;
        r.z = acc[i][2] + bs; r.w = acc[i][3] + bs;
        *(float4*)(Y + b * (CH * HW) + (m0 + (ty << 1) + i) * HW + n0 + (tx << 2)) = r;
    }
}

// ---------------------------------------------------------------------------
// Depthwise 5x5 conv, pad 2.  One block per (bg*64+ch); 256 thr x 4 pixels.
// ---------------------------------------------------------------------------
__global__ __launch_bounds__(256) void dwconv(const float* CK q, const float* CK wdw,
                                              const float* CK bdw, float* CK off) {
    const int bx = blockIdx.x;          // = bg*64 + ch
    const int ch = bx & 63;
    const float* qb = q + bx * HW;
    float w[25];
#pragma unroll
    for (int i = 0; i < 25; i++) w[i] = wdw[ch * 25 + i];
    const float bb = bdw[ch];
    const int t = threadIdx.x;
#pragma unroll
    for (int p = 0; p < 4; p++) {
        int hw = p * 256 + t;
        int ii = hw >> 5, jj = hw & 31;
        float s = bb;
#pragma unroll
        for (int ky = 0; ky < 5; ky++) {
            int y = ii + ky - 2;
            if (y < 0 || y > 31) continue;
#pragma unroll
            for (int kx = 0; kx < 5; kx++) {
                int x = jj + kx - 2;
                if (x < 0 || x > 31) continue;
                s += qb[y * 32 + x] * w[ky * 5 + kx];
            }
        }
        off[bx * HW + hw] = s;
    }
}

// ---------------------------------------------------------------------------
// LayerNorm(ch=64) + exact GELU + 2-ch projection + tanh + ref -> pos.
// ---------------------------------------------------------------------------
__global__ __launch_bounds__(256) void ln_pos(const float* CK off, const float* CK ln_g,
                                              const float* CK ln_b, const float* CK wpj,
                                              float* CK pos_ws, float* CK out_pos,
                                              float* CK out_ref) {
    const int gid = blockIdx.x * 256 + threadIdx.x;
    const int bg = gid >> 10, hw = gid & 1023;
    const float* ob = off + bg * 64 * HW + hw;
    float s1 = 0.f;
#pragma unroll
    for (int c = 0; c < 64; c++) s1 += ob[c * HW];
    const float mean = s1 * 0.015625f;
    float s2 = 0.f;
#pragma unroll
    for (int c = 0; c < 64; c++) { float d = ob[c * HW] - mean; s2 += d * d; }
    const float rs = rsqrtf(s2 * 0.015625f + 1e-5f);
    float p0 = 0.f, p1 = 0.f;
#pragma unroll
    for (int c = 0; c < 64; c++) {
        float vv = (ob[c * HW] - mean) * rs * ln_g[c] + ln_b[c];
        float gl = 0.5f * vv * (1.f + erff(vv * 0.70710678118654752f));
        p0 += gl * wpj[c];
        p1 += gl * wpj[64 + c];
    }
    const int i = hw >> 5, j = hw & 31;
    const float r0 = (j + 0.5f) * 0.0625f - 1.f;   // ref ch0 <- column (meshgrid-xy)
    const float r1 = (i + 0.5f) * 0.0625f - 1.f;   // ref ch1 <- row
    const float pos0 = tanhf(p0) * 0.0625f + r0;   // tanh * (1/32) * ORF(=2)
    const float pos1 = tanhf(p1) * 0.0625f + r1;
    pos_ws[gid * 2] = pos0;  pos_ws[gid * 2 + 1] = pos1;
    out_pos[gid * 2] = pos0; out_pos[gid * 2 + 1] = pos1;
    out_ref[gid * 2] = r0;   out_ref[gid * 2 + 1] = r1;
}

// ---------------------------------------------------------------------------
// Bilinear sample of x (as (16,64,32,32)) at pos -> xs (as (4,256,1024)).
// ---------------------------------------------------------------------------
__global__ __launch_bounds__(256) void sample_xs(const float* CK x, const float* CK pos_ws,
                                                 float* CK xs) {
    const int gid = blockIdx.x * 256 + threadIdx.x;
    const int bg = gid >> 10, n = gid & 1023;
    const float p0 = pos_ws[gid * 2], p1 = pos_ws[gid * 2 + 1];
    const float gx = (p1 + 1.f) * 15.5f, gy = (p0 + 1.f) * 15.5f;   // 0.5*(32-1)
    const float x0f = floorf(gx), y0f = floorf(gy);
    const float wx1 = gx - x0f, wx0 = 1.f - wx1, wy1 = gy - y0f, wy0 = 1.f - wy1;
    const bool vx0 = (x0f >= 0.f) && (x0f <= 31.f);
    const bool vx1 = (x0f >= -1.f) && (x0f <= 30.f);
    const bool vy0 = (y0f >= 0.f) && (y0f <= 31.f);
    const bool vy1 = (y0f >= -1.f) && (y0f <= 30.f);
    const int xi0 = (int)fminf(fmaxf(x0f, 0.f), 31.f);
    const int xi1 = (int)fminf(fmaxf(x0f + 1.f, 0.f), 31.f);
    const int yi0 = (int)fminf(fmaxf(y0f, 0.f), 31.f);
    const int yi1 = (int)fminf(fmaxf(y0f + 1.f, 0.f), 31.f);
    const float w00 = (vy0 && vx0) ? wy0 * wx0 : 0.f;
    const float w01 = (vy0 && vx1) ? wy0 * wx1 : 0.f;
    const float w10 = (vy1 && vx0) ? wy1 * wx0 : 0.f;
    const float w11 = (vy1 && vx1) ? wy1 * wx1 : 0.f;
    const int o00 = yi0 * 32 + xi0, o01 = yi0 * 32 + xi1;
    const int o10 = yi1 * 32 + xi0, o11 = yi1 * 32 + xi1;
    const float* xb = x + bg * 64 * HW;
    float* xo = xs + bg * 64 * HW + n;
#pragma unroll
    for (int c = 0; c < 64; c++) {
        const float* p = xb + c * HW;
        xo[c * HW] = w00 * p[o00] + w01 * p[o01] + w10 * p[o10] + w11 * p[o11];
    }
}

// ---------------------------------------------------------------------------
// Flash attention with RPE bilinear bias — occupancy-restructured.
// grid (16 m-tiles, 32 bh), block 512 = 64 m-slots x 8 n-groups; thread owns
// ONE m row (halves register arrays vs r1).  2 blocks/CU x 8 waves = 16
// waves/CU (was 4).  k/v chunks (32c x 128n) fp32 in LDS (wave-broadcast
// reads); rpe plane (63x63) in LDS; online softmax; 8 n-group partials merged
// via LDS max/sum + atomicAdd into outf.
// ---------------------------------------------------------------------------
__global__ __launch_bounds__(512, 4) void attn_kernel(const float* CK q, const float* CK k,
                                                      const float* CK v, const float* CK pos_ws,
                                                      const float* CK rpe, float* CK out) {
    __shared__ float rpe_s[3969];
    __shared__ float ks[32][128];
    __shared__ float vs[32][128];
    __shared__ float poss[256];              // [n_local][2]
    __shared__ float red[64][8][2];          // [mi][gq][{max,sum}]
    __shared__ float outf[64 * 33];          // [m_local][c], pitch 33
    const int bh = blockIdx.y;
    const int m0 = blockIdx.x * 64;
    const int b = bh >> 3, nh = bh & 7, bg = bh >> 1;
    const int t = threadIdx.x, mi = t & 63, gq = t >> 6;   // gq in 0..7

    const float* rp = rpe + nh * 3969;
    for (int i = t; i < 3969; i += 512) rpe_s[i] = rp[i];
    for (int i = t; i < 64 * 33; i += 512) outf[i] = 0.f;

    const float* qb = q + (b * 256 + nh * 32) * HW + m0 + mi;
    float qr[32];
#pragma unroll
    for (int c = 0; c < 32; c++) qr[c] = qb[c * HW];
    const int m = m0 + mi;
    const float qg0 = ((m & 31) + 0.5f) * 0.0625f - 1.f;
    const float qg1 = ((m >> 5) + 0.5f) * 0.0625f - 1.f;
    float oacc[32] = {};
    float rmax = -1e30f, rsum = 0.f;
    const float* kb = k + (b * 256 + nh * 32) * HW;
    const float* vb = v + (b * 256 + nh * 32) * HW;
    const float* pb = pos_ws + bg * 2048;

    for (int nc = 0; nc < 8; nc++) {
        __syncthreads();
#pragma unroll
        for (int l = 0; l < 2; l++) {
            int f4 = t + l * 512;                       // 0..1023
            int c_l = f4 >> 5, n_l = (f4 & 31) << 2;
            *(float4*)&ks[c_l][n_l] = *(const float4*)(kb + c_l * HW + nc * 128 + n_l);
            *(float4*)&vs[c_l][n_l] = *(const float4*)(vb + c_l * HW + nc * 128 + n_l);
        }
        if (t < 256) poss[t] = pb[nc * 256 + t];
        __syncthreads();

        for (int ng = 0; ng < 4; ng++) {
            const int nl0 = gq * 16 + ng * 4;
            float dot[4] = {};
#pragma unroll
            for (int c = 0; c < 32; c++) {
                float4 k4 = *(const float4*)&ks[c][nl0];   // wave-broadcast
                dot[0] += qr[c] * k4.x; dot[1] += qr[c] * k4.y;
                dot[2] += qr[c] * k4.z; dot[3] += qr[c] * k4.w;
            }
            float s[4];
#pragma unroll
            for (int j = 0; j < 4; j++) {
                const float pp0 = poss[(nl0 + j) * 2], pp1 = poss[(nl0 + j) * 2 + 1];
                float d0 = (qg0 - pp0) * 0.5f, d1 = (qg1 - pp1) * 0.5f;
                float gx = (d1 + 1.f) * 31.f, gy = (d0 + 1.f) * 31.f;  // 0.5*(63-1)
                float x0f = floorf(gx), y0f = floorf(gy);
                float wx1 = gx - x0f, wx0 = 1.f - wx1;
                float wy1 = gy - y0f, wy0 = 1.f - wy1;
                bool vx0 = (x0f >= 0.f) && (x0f <= 62.f);
                bool vx1 = (x0f >= -1.f) && (x0f <= 61.f);
                bool vy0 = (y0f >= 0.f) && (y0f <= 62.f);
                bool vy1 = (y0f >= -1.f) && (y0f <= 61.f);
                int xi0 = (int)fminf(fmaxf(x0f, 0.f), 62.f);
                int xi1 = (int)fminf(fmaxf(x0f + 1.f, 0.f), 62.f);
                int yi0 = (int)fminf(fmaxf(y0f, 0.f), 62.f);
                int yi1 = (int)fminf(fmaxf(y0f + 1.f, 0.f), 62.f);
                float w00 = (vy0 && vx0) ? wy0 * wx0 : 0.f;
                float w01 = (vy0 && vx1) ? wy0 * wx1 : 0.f;
                float w10 = (vy1 && vx0) ? wy1 * wx0 : 0.f;
                float w11 = (vy1 && vx1) ? wy1 * wx1 : 0.f;
                float bias = w00 * rpe_s[yi0 * 63 + xi0] + w01 * rpe_s[yi0 * 63 + xi1]
                           + w10 * rpe_s[yi1 * 63 + xi0] + w11 * rpe_s[yi1 * 63 + xi1];
                s[j] = dot[j] * 0.17677669529663687f + bias;
            }
            float gm = fmaxf(fmaxf(s[0], s[1]), fmaxf(s[2], s[3]));
            if (gm > rmax) {
                float corr = __expf(rmax - gm);
                rsum *= corr;
#pragma unroll
                for (int c = 0; c < 32; c++) oacc[c] *= corr;
                rmax = gm;
            }
            float wgt[4];
#pragma unroll
            for (int j = 0; j < 4; j++) wgt[j] = __expf(s[j] - rmax);
            rsum += wgt[0] + wgt[1] + wgt[2] + wgt[3];
#pragma unroll
            for (int c = 0; c < 32; c++) {
                float4 v4 = *(const float4*)&vs[c][nl0];   // wave-broadcast
                oacc[c] += wgt[0] * v4.x + wgt[1] * v4.y + wgt[2] * v4.z + wgt[3] * v4.w;
            }
        }
    }

    __syncthreads();
    red[mi][gq][0] = rmax; red[mi][gq][1] = rsum;
    __syncthreads();
    {
        float M = red[mi][0][0];
#pragma unroll
        for (int g2 = 1; g2 < 8; g2++) M = fmaxf(M, red[mi][g2][0]);
        float S = 0.f;
#pragma unroll
        for (int g2 = 0; g2 < 8; g2++) S += red[mi][g2][1] * __expf(red[mi][g2][0] - M);
        float f = __expf(rmax - M) / S;
#pragma unroll
        for (int c = 0; c < 32; c++) atomicAdd(&outf[mi * 33 + c], oacc[c] * f);
    }
    __syncthreads();
    {
        float* ob = out + (b * 256 + nh * 32) * HW + m0;
        int ml = t & 63, cq = t >> 6;
#pragma unroll
        for (int cc = 0; cc < 4; cc++) {
            int c = cq * 4 + cc;
            ob[c * HW + ml] = outf[ml * 33 + c];
        }
    }
}

// ---------------------------------------------------------------------------
extern "C" void kernel_launch(void* const* d_in, const int* in_sizes, int n_in,
                              void* d_out, int out_size, void* d_ws, size_t ws_size,
                              hipStream_t stream) {
    (void)in_sizes; (void)n_in; (void)out_size; (void)ws_size;
    const float* x   = (const float*)d_in[0];
    const float* wq  = (const float*)d_in[1];
    const float* bq  = (const float*)d_in[2];
    const float* wdw = (const float*)d_in[3];
    const float* bdw = (const float*)d_in[4];
    const float* lng = (const float*)d_in[5];
    const float* lnb = (const float*)d_in[6];
    const float* wpj = (const float*)d_in[7];
    const float* wk  = (const float*)d_in[8];
    const float* bk  = (const float*)d_in[9];
    const float* wv  = (const float*)d_in[10];
    const float* bv  = (const float*)d_in[11];
    const float* wo  = (const float*)d_in[12];
    const float* bo  = (const float*)d_in[13];
    const float* rpe = (const float*)d_in[14];
    float* outp = (float*)d_out;
    float* ws = (float*)d_ws;

    float* q_ws    = ws;                 // 1M floats
    float* off_ws  = ws + (1 << 20);     // 1M floats (reused as attention output)
    float* xs_ws   = ws + (2 << 20);     // 1M floats
    float* k_ws    = ws + (3 << 20);     // 1M floats
    float* v_ws    = ws + (4 << 20);     // 1M floats
    float* pos_ws  = ws + (5 << 20);     // 32K floats
    float* attno_ws = off_ws;

    gemm64x32<<<dim3(32, 4, 4), 256, 0, stream>>>(x, wq, bq, q_ws, wq, bq, q_ws);
    dwconv<<<1024, 256, 0, stream>>>(q_ws, wdw, bdw, off_ws);
    ln_pos<<<64, 256, 0, stream>>>(off_ws, lng, lnb, wpj, pos_ws,
                                   outp + (1 << 20), outp + (1 << 20) + 32768);
    sample_xs<<<64, 256, 0, stream>>>(x, pos_ws, xs_ws);
    gemm64x32<<<dim3(32, 4, 8), 256, 0, stream>>>(xs_ws, wk, bk, k_ws, wv, bv, v_ws);
    attn_kernel<<<dim3(16, 32), 512, 0, stream>>>(q_ws, k_ws, v_ws, pos_ws, rpe, attno_ws);
    gemm64x32<<<dim3(32, 4, 4), 256, 0, stream>>>(attno_ws, wo, bo, outp, wo, bo, outp);
}

// Round 3
// 270.561 us; speedup vs baseline: 1.6982x; 1.4092x over previous
//
#include <hip/hip_runtime.h>
#include <math.h>

#define CK __restrict__

constexpr int CH = 256;
constexpr int HW = 1024;   // 32*32

typedef __attribute__((ext_vector_type(8))) short short8;
typedef __attribute__((ext_vector_type(4))) float f32x4;

__device__ __forceinline__ ushort f2b(float x) {   // fp32 -> bf16 RNE
    union { float f; unsigned int u; } a; a.f = x;
    unsigned int r = (a.u + 0x7FFFu + ((a.u >> 16) & 1u)) >> 16;
    return (ushort)r;
}

// ---------------------------------------------------------------------------
// GEMM: Y[b][o][n] = sum_c W[o*256+c] * X[b][c][n] + bias[o]   (fp32 out)
// Tile 64(m) x 32(n), 256 threads, micro 2x4.  z&3 = b, z>>2 selects set.
// ---------------------------------------------------------------------------
__global__ __launch_bounds__(256) void gemm64x32(const float* CK X,
                                                 const float* CK W0, const float* CK b0, float* CK Y0,
                                                 const float* CK W1, const float* CK b1, float* CK Y1) {
    __shared__ float Ws[16][68];
    __shared__ float Xs[16][32];
    const int b   = blockIdx.z & 3;
    const int sel = blockIdx.z >> 2;
    const float* W    = sel ? W1 : W0;
    const float* bias = sel ? b1 : b0;
    float* Y          = sel ? Y1 : Y0;
    const int m0 = blockIdx.y * 64, n0 = blockIdx.x * 32;
    const int t  = threadIdx.x;
    const int tx = t & 7, ty = t >> 3;
    const float* Xb = X + b * (CH * HW);
    float acc[2][4] = {};
    for (int k0 = 0; k0 < 256; k0 += 16) {
        {
            int o_l = t >> 2, c_l = (t & 3) << 2;
            const float4 w4 = *(const float4*)(W + (m0 + o_l) * 256 + k0 + c_l);
            Ws[c_l + 0][o_l] = w4.x; Ws[c_l + 1][o_l] = w4.y;
            Ws[c_l + 2][o_l] = w4.z; Ws[c_l + 3][o_l] = w4.w;
        }
        if (t < 128) {
            int c_l = t >> 3, n_l = (t & 7) << 2;
            *(float4*)&Xs[c_l][n_l] = *(const float4*)(Xb + (k0 + c_l) * HW + n0 + n_l);
        }
        __syncthreads();
#pragma unroll
        for (int kk = 0; kk < 16; kk++) {
            float2 a2 = *(const float2*)&Ws[kk][ty << 1];
            float4 b4 = *(const float4*)&Xs[kk][tx << 2];
            acc[0][0] += a2.x * b4.x; acc[0][1] += a2.x * b4.y;
            acc[0][2] += a2.x * b4.z; acc[0][3] += a2.x * b4.w;
            acc[1][0] += a2.y * b4.x; acc[1][1] += a2.y * b4.y;
            acc[1][2] += a2.y * b4.z; acc[1][3] += a2.y * b4.w;
        }
        __syncthreads();
    }
#pragma unroll
    for (int i = 0; i < 2; i++) {
        float bs = bias[m0 + (ty << 1) + i];
        float4 r;
        r.x = acc[i][0] + bs; r.y = acc[i][1] + bs;
        r.z = acc[i][2] + bs; r.w = acc[i][3] + bs;
        *(float4*)(Y + b * (CH * HW) + (m0 + (ty << 1) + i) * HW + n0 + (tx << 2)) = r;
    }
}

// ---------------------------------------------------------------------------
// K/V GEMM with bf16 outputs for the MFMA attention:
//   sel 0: K  -> kbt bf16, layout [b*8+nh][n][32c]   (transposed)
//   sel 1: V  -> vbs bf16, layout [b][256ch][n]
// ---------------------------------------------------------------------------
__global__ __launch_bounds__(256) void gemm_kv(const float* CK X,
                                               const float* CK Wk, const float* CK bk, ushort* CK kbt,
                                               const float* CK Wv, const float* CK bv, ushort* CK vbs) {
    __shared__ float Ws[16][68];
    __shared__ float Xs[16][32];
    const int b   = blockIdx.z & 3;
    const int sel = blockIdx.z >> 2;
    const float* W    = sel ? Wv : Wk;
    const float* bias = sel ? bv : bk;
    const int m0 = blockIdx.y * 64, n0 = blockIdx.x * 32;
    const int t  = threadIdx.x;
    const int tx = t & 7, ty = t >> 3;
    const float* Xb = X + b * (CH * HW);
    float acc[2][4] = {};
    for (int k0 = 0; k0 < 256; k0 += 16) {
        {
            int o_l = t >> 2, c_l = (t & 3) << 2;
            const float4 w4 = *(const float4*)(W + (m0 + o_l) * 256 + k0 + c_l);
            Ws[c_l + 0][o_l] = w4.x; Ws[c_l + 1][o_l] = w4.y;
            Ws[c_l + 2][o_l] = w4.z; Ws[c_l + 3][o_l] = w4.w;
        }
        if (t < 128) {
            int c_l = t >> 3, n_l = (t & 7) << 2;
            *(float4*)&Xs[c_l][n_l] = *(const float4*)(Xb + (k0 + c_l) * HW + n0 + n_l);
        }
        __syncthreads();
#pragma unroll
        for (int kk = 0; kk < 16; kk++) {
            float2 a2 = *(const float2*)&Ws[kk][ty << 1];
            float4 b4 = *(const float4*)&Xs[kk][tx << 2];
            acc[0][0] += a2.x * b4.x; acc[0][1] += a2.x * b4.y;
            acc[0][2] += a2.x * b4.z; acc[0][3] += a2.x * b4.w;
            acc[1][0] += a2.y * b4.x; acc[1][1] += a2.y * b4.y;
            acc[1][2] += a2.y * b4.z; acc[1][3] += a2.y * b4.w;
        }
        __syncthreads();
    }
#pragma unroll
    for (int i = 0; i < 2; i++) {
        const int o = m0 + (ty << 1) + i;
        const float bs = bias[o];
        if (sel == 0) {
            ushort* kb = kbt + ((b * 8 + (o >> 5)) * 1024) * 32 + (o & 31);
#pragma unroll
            for (int j = 0; j < 4; j++) {
                int n = n0 + (tx << 2) + j;
                kb[n * 32] = f2b(acc[i][j] + bs);
            }
        } else {
            ushort4 r;
            r.x = f2b(acc[i][0] + bs); r.y = f2b(acc[i][1] + bs);
            r.z = f2b(acc[i][2] + bs); r.w = f2b(acc[i][3] + bs);
            *(ushort4*)(vbs + (b * 256 + o) * 1024 + n0 + (tx << 2)) = r;
        }
    }
}

// ---------------------------------------------------------------------------
// Depthwise 5x5 conv, pad 2.
// ---------------------------------------------------------------------------
__global__ __launch_bounds__(256) void dwconv(const float* CK q, const float* CK wdw,
                                              const float* CK bdw, float* CK off) {
    const int bx = blockIdx.x;
    const int ch = bx & 63;
    const float* qb = q + bx * HW;
    float w[25];
#pragma unroll
    for (int i = 0; i < 25; i++) w[i] = wdw[ch * 25 + i];
    const float bb = bdw[ch];
    const int t = threadIdx.x;
#pragma unroll
    for (int p = 0; p < 4; p++) {
        int hw = p * 256 + t;
        int ii = hw >> 5, jj = hw & 31;
        float s = bb;
#pragma unroll
        for (int ky = 0; ky < 5; ky++) {
            int y = ii + ky - 2;
            if (y < 0 || y > 31) continue;
#pragma unroll
            for (int kx = 0; kx < 5; kx++) {
                int x = jj + kx - 2;
                if (x < 0 || x > 31) continue;
                s += qb[y * 32 + x] * w[ky * 5 + kx];
            }
        }
        off[bx * HW + hw] = s;
    }
}

// ---------------------------------------------------------------------------
// LayerNorm(ch=64) + exact GELU + 2-ch projection + tanh + ref -> pos.
// ---------------------------------------------------------------------------
__global__ __launch_bounds__(256) void ln_pos(const float* CK off, const float* CK ln_g,
                                              const float* CK ln_b, const float* CK wpj,
                                              float* CK pos_ws, float* CK out_pos,
                                              float* CK out_ref) {
    const int gid = blockIdx.x * 256 + threadIdx.x;
    const int bg = gid >> 10, hw = gid & 1023;
    const float* ob = off + bg * 64 * HW + hw;
    float s1 = 0.f;
#pragma unroll
    for (int c = 0; c < 64; c++) s1 += ob[c * HW];
    const float mean = s1 * 0.015625f;
    float s2 = 0.f;
#pragma unroll
    for (int c = 0; c < 64; c++) { float d = ob[c * HW] - mean; s2 += d * d; }
    const float rs = rsqrtf(s2 * 0.015625f + 1e-5f);
    float p0 = 0.f, p1 = 0.f;
#pragma unroll
    for (int c = 0; c < 64; c++) {
        float vv = (ob[c * HW] - mean) * rs * ln_g[c] + ln_b[c];
        float gl = 0.5f * vv * (1.f + erff(vv * 0.70710678118654752f));
        p0 += gl * wpj[c];
        p1 += gl * wpj[64 + c];
    }
    const int i = hw >> 5, j = hw & 31;
    const float r0 = (j + 0.5f) * 0.0625f - 1.f;
    const float r1 = (i + 0.5f) * 0.0625f - 1.f;
    const float pos0 = tanhf(p0) * 0.0625f + r0;
    const float pos1 = tanhf(p1) * 0.0625f + r1;
    pos_ws[gid * 2] = pos0;  pos_ws[gid * 2 + 1] = pos1;
    out_pos[gid * 2] = pos0; out_pos[gid * 2 + 1] = pos1;
    out_ref[gid * 2] = r0;   out_ref[gid * 2 + 1] = r1;
}

// ---------------------------------------------------------------------------
// Bilinear sample of x at pos -> xs.
// ---------------------------------------------------------------------------
__global__ __launch_bounds__(256) void sample_xs(const float* CK x, const float* CK pos_ws,
                                                 float* CK xs) {
    const int gid = blockIdx.x * 256 + threadIdx.x;
    const int bg = gid >> 10, n = gid & 1023;
    const float p0 = pos_ws[gid * 2], p1 = pos_ws[gid * 2 + 1];
    const float gx = (p1 + 1.f) * 15.5f, gy = (p0 + 1.f) * 15.5f;
    const float x0f = floorf(gx), y0f = floorf(gy);
    const float wx1 = gx - x0f, wx0 = 1.f - wx1, wy1 = gy - y0f, wy0 = 1.f - wy1;
    const bool vx0 = (x0f >= 0.f) && (x0f <= 31.f);
    const bool vx1 = (x0f >= -1.f) && (x0f <= 30.f);
    const bool vy0 = (y0f >= 0.f) && (y0f <= 31.f);
    const bool vy1 = (y0f >= -1.f) && (y0f <= 30.f);
    const int xi0 = (int)fminf(fmaxf(x0f, 0.f), 31.f);
    const int xi1 = (int)fminf(fmaxf(x0f + 1.f, 0.f), 31.f);
    const int yi0 = (int)fminf(fmaxf(y0f, 0.f), 31.f);
    const int yi1 = (int)fminf(fmaxf(y0f + 1.f, 0.f), 31.f);
    const float w00 = (vy0 && vx0) ? wy0 * wx0 : 0.f;
    const float w01 = (vy0 && vx1) ? wy0 * wx1 : 0.f;
    const float w10 = (vy1 && vx0) ? wy1 * wx0 : 0.f;
    const float w11 = (vy1 && vx1) ? wy1 * wx1 : 0.f;
    const int o00 = yi0 * 32 + xi0, o01 = yi0 * 32 + xi1;
    const int o10 = yi1 * 32 + xi0, o11 = yi1 * 32 + xi1;
    const float* xb = x + bg * 64 * HW;
    float* xo = xs + bg * 64 * HW + n;
#pragma unroll
    for (int c = 0; c < 64; c++) {
        const float* p = xb + c * HW;
        xo[c * HW] = w00 * p[o00] + w01 * p[o01] + w10 * p[o10] + w11 * p[o11];
    }
}

// ---------------------------------------------------------------------------
// MFMA flash attention with RPE bilinear bias.
// grid (16 m-tiles, 32 bh), block 256 = 4 waves; wave w owns 16 m rows.
// S^T = K^T * Q via mfma_16x16x32_bf16 (D: lane holds 4 n-rows, m=lane&15);
// softmax in-lane + 2 shfl_xor; P -> bf16 via wave-private LDS; O^T = V * P^T.
// rpe plane padded 65x65 with zero ring -> clamp-only boundary handling.
// ---------------------------------------------------------------------------
__global__ __launch_bounds__(256) void attn_mfma(const float* CK q, const ushort* CK kbt,
                                                 const ushort* CK vbs, const float* CK pos_ws,
                                                 const float* CK rpe, float* CK out) {
    __shared__ float rpe_p[65 * 65];
    __shared__ ushort ksb[128 * 32];      // [n][c] bf16
    __shared__ ushort vsb[32 * 136];      // [c][n] bf16, pitch 136
    __shared__ ushort Pl[4 * 16 * 136];   // per-wave [m][n] bf16, pitch 136
    __shared__ float poss[256];           // [n][2]
    const int bh = blockIdx.y;
    const int b = bh >> 3, nh = bh & 7, bg = bh >> 1;
    const int t = threadIdx.x;
    const int w = t >> 6, l = t & 63;
    const int lm = l & 15, qd = l >> 4;
    const int mbase = blockIdx.x * 64 + w * 16;

    // padded rpe plane
    for (int i = t; i < 65 * 65; i += 256) rpe_p[i] = 0.f;
    __syncthreads();
    {
        const float* rp = rpe + nh * 3969;
        for (int i = t; i < 3969; i += 256) {
            int y = i / 63, x = i - y * 63;
            rpe_p[(y + 1) * 65 + (x + 1)] = rp[i];
        }
    }

    // Q B-fragment (one-time): B[k=c=qd*8+j][col=m=lm]
    const int m = mbase + lm;
    short8 qf;
    {
        const float* qb = q + (b * 256 + nh * 32) * HW + m;
#pragma unroll
        for (int j = 0; j < 8; j++) qf[j] = (short)f2b(qb[(qd * 8 + j) * HW]);
    }
    const float qg0 = ((m & 31) + 0.5f) * 0.0625f - 1.f;
    const float qg1 = ((m >> 5) + 0.5f) * 0.0625f - 1.f;
    const float ax = 31.f + 15.5f * qg1;   // gx = ax - 15.5*pos1
    const float ay = 31.f + 15.5f * qg0;   // gy = ay - 15.5*pos0

    f32x4 oacc0 = {0.f, 0.f, 0.f, 0.f}, oacc1 = {0.f, 0.f, 0.f, 0.f};
    float rmax = -3e38f, rsum = 0.f;
    const ushort* kg = kbt + bh * 1024 * 32;
    const ushort* vg = vbs + (b * 256 + nh * 32) * HW;
    const float* pb = pos_ws + bg * 2048;
    ushort* PlW = Pl + w * (16 * 136);

    for (int nc = 0; nc < 8; nc++) {
        __syncthreads();
        {   // stage K chunk (contiguous 8KB) and V chunk (row-remapped, pitch 136)
            const int4* src = (const int4*)(kg + nc * 128 * 32);
            int4* dst = (int4*)ksb;
            dst[t] = src[t]; dst[t + 256] = src[t + 256];
#pragma unroll
            for (int i = 0; i < 2; i++) {
                int flat = t + i * 256;                 // 0..511
                int c = flat >> 4, n8 = (flat & 15) << 3;
                *(int4*)(vsb + c * 136 + n8) = *(const int4*)(vg + c * HW + nc * 128 + n8);
            }
            poss[t] = pb[nc * 256 + t];
        }
        __syncthreads();

        // QK^T: S^T[n][m], 8 MFMAs
        f32x4 sT[8];
#pragma unroll
        for (int nb = 0; nb < 8; nb++) {
            short8 kf = *(const short8*)(ksb + (nb * 16 + lm) * 32 + qd * 8);
            sT[nb] = __builtin_amdgcn_mfma_f32_16x16x32_bf16(kf, qf,
                        (f32x4){0.f, 0.f, 0.f, 0.f}, 0, 0, 0);
        }

        // bias + scale, track chunk max
        float cmax = -3e38f;
#pragma unroll
        for (int nb = 0; nb < 8; nb++) {
#pragma unroll
            for (int r = 0; r < 4; r++) {
                const int nl = nb * 16 + qd * 4 + r;
                const float gx = ax - 15.5f * poss[nl * 2 + 1];
                const float gy = ay - 15.5f * poss[nl * 2 + 0];
                const float x0f = floorf(gx), y0f = floorf(gy);
                const float wx1 = gx - x0f, wy1 = gy - y0f;
                const int xi = (int)x0f, yi = (int)y0f;
                const int x0c = min(64, max(0, xi + 1));
                const int x1c = min(64, max(0, xi + 2));
                const int y0c = min(64, max(0, yi + 1));
                const int y1c = min(64, max(0, yi + 2));
                const float* r0p = rpe_p + y0c * 65;
                const float* r1p = rpe_p + y1c * 65;
                const float bias = (1.f - wy1) * ((1.f - wx1) * r0p[x0c] + wx1 * r0p[x1c])
                                 + wy1 * ((1.f - wx1) * r1p[x0c] + wx1 * r1p[x1c]);
                sT[nb][r] = sT[nb][r] * 0.17677669529663687f + bias;
                cmax = fmaxf(cmax, sT[nb][r]);
            }
        }
        cmax = fmaxf(cmax, __shfl_xor(cmax, 16));
        cmax = fmaxf(cmax, __shfl_xor(cmax, 32));
        const float newmax = fmaxf(rmax, cmax);
        const float alpha = __expf(rmax - newmax);
        rmax = newmax;

        // P = exp(s - max) -> bf16 into wave-private LDS [m][n]
        float csum = 0.f;
#pragma unroll
        for (int nb = 0; nb < 8; nb++) {
            float e0 = __expf(sT[nb][0] - rmax);
            float e1 = __expf(sT[nb][1] - rmax);
            float e2 = __expf(sT[nb][2] - rmax);
            float e3 = __expf(sT[nb][3] - rmax);
            csum += (e0 + e1) + (e2 + e3);
            uint2 pk;
            pk.x = (unsigned int)f2b(e0) | ((unsigned int)f2b(e1) << 16);
            pk.y = (unsigned int)f2b(e2) | ((unsigned int)f2b(e3) << 16);
            *(uint2*)(PlW + lm * 136 + nb * 16 + qd * 4) = pk;
        }
        csum += __shfl_xor(csum, 16);
        csum += __shfl_xor(csum, 32);
        rsum = rsum * alpha + csum;
        oacc0 *= alpha;
        oacc1 *= alpha;

        // PV: O^T[c][m] += V[c][n] * P^T[n][m], 8 MFMAs
#pragma unroll
        for (int kc = 0; kc < 4; kc++) {
            short8 pf  = *(const short8*)(PlW + lm * 136 + kc * 32 + qd * 8);
            short8 vf0 = *(const short8*)(vsb + lm * 136 + kc * 32 + qd * 8);
            short8 vf1 = *(const short8*)(vsb + (16 + lm) * 136 + kc * 32 + qd * 8);
            oacc0 = __builtin_amdgcn_mfma_f32_16x16x32_bf16(vf0, pf, oacc0, 0, 0, 0);
            oacc1 = __builtin_amdgcn_mfma_f32_16x16x32_bf16(vf1, pf, oacc1, 0, 0, 0);
        }
    }

    const float inv = 1.f / rsum;
    float* ob = out + (b * 256 + nh * 32) * HW + m;
#pragma unroll
    for (int r = 0; r < 4; r++) {
        const int c0 = qd * 4 + r;
        ob[c0 * HW]        = oacc0[r] * inv;
        ob[(16 + c0) * HW] = oacc1[r] * inv;
    }
}

// ---------------------------------------------------------------------------
extern "C" void kernel_launch(void* const* d_in, const int* in_sizes, int n_in,
                              void* d_out, int out_size, void* d_ws, size_t ws_size,
                              hipStream_t stream) {
    (void)in_sizes; (void)n_in; (void)out_size; (void)ws_size;
    const float* x   = (const float*)d_in[0];
    const float* wq  = (const float*)d_in[1];
    const float* bq  = (const float*)d_in[2];
    const float* wdw = (const float*)d_in[3];
    const float* bdw = (const float*)d_in[4];
    const float* lng = (const float*)d_in[5];
    const float* lnb = (const float*)d_in[6];
    const float* wpj = (const float*)d_in[7];
    const float* wk  = (const float*)d_in[8];
    const float* bk  = (const float*)d_in[9];
    const float* wv  = (const float*)d_in[10];
    const float* bv  = (const float*)d_in[11];
    const float* wo  = (const float*)d_in[12];
    const float* bo  = (const float*)d_in[13];
    const float* rpe = (const float*)d_in[14];
    float* outp = (float*)d_out;
    float* ws = (float*)d_ws;

    float* q_ws    = ws;                      // 1M floats
    float* off_ws  = ws + (1 << 20);          // 1M floats (reused as attn output)
    float* xs_ws   = ws + (2 << 20);          // 1M floats
    ushort* kbt_ws = (ushort*)(ws + (3 << 20)); // 1M bf16 (2MB)
    ushort* vbs_ws = (ushort*)(ws + (4 << 20)); // 1M bf16 (2MB)
    float* pos_ws  = ws + (5 << 20);          // 32K floats
    float* attno_ws = off_ws;

    gemm64x32<<<dim3(32, 4, 4), 256, 0, stream>>>(x, wq, bq, q_ws, wq, bq, q_ws);
    dwconv<<<1024, 256, 0, stream>>>(q_ws, wdw, bdw, off_ws);
    ln_pos<<<64, 256, 0, stream>>>(off_ws, lng, lnb, wpj, pos_ws,
                                   outp + (1 << 20), outp + (1 << 20) + 32768);
    sample_xs<<<64, 256, 0, stream>>>(x, pos_ws, xs_ws);
    gemm_kv<<<dim3(32, 4, 8), 256, 0, stream>>>(xs_ws, wk, bk, kbt_ws, wv, bv, vbs_ws);
    attn_mfma<<<dim3(16, 32), 256, 0, stream>>>(q_ws, kbt_ws, vbs_ws, pos_ws, rpe, attno_ws);
    gemm64x32<<<dim3(32, 4, 4), 256, 0, stream>>>(attno_ws, wo, bo, outp, wo, bo, outp);
}

// Round 4
// 220.937 us; speedup vs baseline: 2.0796x; 1.2246x over previous
//
#include <hip/hip_runtime.h>
#include <math.h>

#define CK __restrict__

constexpr int CH = 256;
constexpr int HW = 1024;   // 32*32

typedef __attribute__((ext_vector_type(8))) short short8;
typedef __attribute__((ext_vector_type(4))) float f32x4;

__device__ __forceinline__ ushort f2b(float x) {   // fp32 -> bf16 RNE
    union { float f; unsigned int u; } a; a.f = x;
    unsigned int r = (a.u + 0x7FFFu + ((a.u >> 16) & 1u)) >> 16;
    return (ushort)r;
}
__device__ __forceinline__ short8 ld8(const ushort* p) { return *(const short8*)p; }

// ---------------------------------------------------------------------------
// Convert the four 256x256 fp32 weight matrices to bf16 (row-major kept).
// grid (64, 4): y picks matrix, 256 thr x 1 float4.
// ---------------------------------------------------------------------------
__global__ __launch_bounds__(256) void convw(const float* CK w0, const float* CK w1,
                                             const float* CK w2, const float* CK w3,
                                             ushort* CK o0, ushort* CK o1,
                                             ushort* CK o2, ushort* CK o3) {
    const float* src; ushort* dst;
    switch (blockIdx.y) {
        case 0: src = w0; dst = o0; break;
        case 1: src = w1; dst = o1; break;
        case 2: src = w2; dst = o2; break;
        default: src = w3; dst = o3; break;
    }
    const int i = blockIdx.x * 256 + threadIdx.x;   // 16384 float4 per matrix
    float4 v = ((const float4*)src)[i];
    ushort4 r; r.x = f2b(v.x); r.y = f2b(v.y); r.z = f2b(v.z); r.w = f2b(v.w);
    ((ushort4*)dst)[i] = r;
}

// ---------------------------------------------------------------------------
// x fp32 [b][256c][1024n] -> xT bf16 [b][1024n][256c].
// grid (32 c8-groups, 4 b); coalesced row reads, 16B packed stores.
// ---------------------------------------------------------------------------
__global__ __launch_bounds__(256) void convx(const float* CK x, ushort* CK xT) {
    const int c8 = blockIdx.x, b = blockIdx.y, t = threadIdx.x;
    for (int nn = 0; nn < 4; nn++) {
        const int n = nn * 256 + t;
        union { ushort u[8]; short8 s; } pk;
#pragma unroll
        for (int j = 0; j < 8; j++) pk.u[j] = f2b(x[(b * 256 + c8 * 8 + j) * HW + n]);
        *(short8*)(xT + b * 262144 + n * 256 + c8 * 8) = pk.s;
    }
}

// ---------------------------------------------------------------------------
// MFMA GEMM, fp32 out: Y[b][m][n] = sum_c W[m][c] * A^T[n][c] + bias[m].
// LDS-free: A-frags (X^T rows) and B-frags (W rows) are contiguous 16B loads.
// grid (16 nt, 4 mt, 4 b), 256 thr = 4 waves, wave = 32m x 32n.
// ---------------------------------------------------------------------------
__global__ __launch_bounds__(256) void gemm_f32(const ushort* CK AT, const ushort* CK W,
                                                const float* CK bias, float* CK Y) {
    const int b = blockIdx.z;
    const int t = threadIdx.x, w = t >> 6, l = t & 63;
    const int lm = l & 15, qd = l >> 4;
    const int m0 = blockIdx.y * 64 + (w & 1) * 32;
    const int n0 = blockIdx.x * 64 + (w >> 1) * 32;
    const ushort* A = AT + b * 262144 + n0 * 256;
    const ushort* Bm = W + m0 * 256;
    f32x4 acc[2][2] = {};
#pragma unroll
    for (int k0 = 0; k0 < 8; k0++) {
        const int ko = k0 * 32 + qd * 8;
        short8 a0 = ld8(A + lm * 256 + ko);
        short8 a1 = ld8(A + (16 + lm) * 256 + ko);
        short8 b0 = ld8(Bm + lm * 256 + ko);
        short8 b1 = ld8(Bm + (16 + lm) * 256 + ko);
        acc[0][0] = __builtin_amdgcn_mfma_f32_16x16x32_bf16(a0, b0, acc[0][0], 0, 0, 0);
        acc[0][1] = __builtin_amdgcn_mfma_f32_16x16x32_bf16(a0, b1, acc[0][1], 0, 0, 0);
        acc[1][0] = __builtin_amdgcn_mfma_f32_16x16x32_bf16(a1, b0, acc[1][0], 0, 0, 0);
        acc[1][1] = __builtin_amdgcn_mfma_f32_16x16x32_bf16(a1, b1, acc[1][1], 0, 0, 0);
    }
#pragma unroll
    for (int in = 0; in < 2; in++)
#pragma unroll
        for (int im = 0; im < 2; im++) {
            const int m = m0 + im * 16 + lm;
            const float bs = bias[m];
            const int nb_ = n0 + in * 16 + qd * 4;
            float4 r;
            r.x = acc[in][im][0] + bs; r.y = acc[in][im][1] + bs;
            r.z = acc[in][im][2] + bs; r.w = acc[in][im][3] + bs;
            *(float4*)(Y + b * (CH * HW) + m * HW + nb_) = r;
        }
}

// ---------------------------------------------------------------------------
// Fused K+V MFMA GEMM from xs^T; emits bf16 in attention-fragment-linear
// global layouts:
//   K: cell = [(bh*8+nc)*512 + nb*64 + qd_c*16 + lm_n]*8 + co_c
//   V: cell = [(bh*8+nc)*512 + (cb*4+kc)*64 + qd_n*16 + lm_c]*8 + co_n
// ---------------------------------------------------------------------------
__global__ __launch_bounds__(256) void gemm_kv(const ushort* CK AT,
                                               const ushort* CK Wk, const float* CK bk, ushort* CK kbt,
                                               const ushort* CK Wv, const float* CK bv, ushort* CK vbs) {
    const int b = blockIdx.z;
    const int t = threadIdx.x, w = t >> 6, l = t & 63;
    const int lm = l & 15, qd = l >> 4;
    const int m0 = blockIdx.y * 64 + (w & 1) * 32;
    const int n0 = blockIdx.x * 64 + (w >> 1) * 32;
    const ushort* A = AT + b * 262144 + n0 * 256;
    const ushort* Bk = Wk + m0 * 256;
    const ushort* Bv = Wv + m0 * 256;
    f32x4 ak[2][2] = {}, av[2][2] = {};
#pragma unroll
    for (int k0 = 0; k0 < 8; k0++) {
        const int ko = k0 * 32 + qd * 8;
        short8 a0 = ld8(A + lm * 256 + ko);
        short8 a1 = ld8(A + (16 + lm) * 256 + ko);
        short8 k0f = ld8(Bk + lm * 256 + ko);
        short8 k1f = ld8(Bk + (16 + lm) * 256 + ko);
        short8 v0f = ld8(Bv + lm * 256 + ko);
        short8 v1f = ld8(Bv + (16 + lm) * 256 + ko);
        ak[0][0] = __builtin_amdgcn_mfma_f32_16x16x32_bf16(a0, k0f, ak[0][0], 0, 0, 0);
        ak[0][1] = __builtin_amdgcn_mfma_f32_16x16x32_bf16(a0, k1f, ak[0][1], 0, 0, 0);
        ak[1][0] = __builtin_amdgcn_mfma_f32_16x16x32_bf16(a1, k0f, ak[1][0], 0, 0, 0);
        ak[1][1] = __builtin_amdgcn_mfma_f32_16x16x32_bf16(a1, k1f, ak[1][1], 0, 0, 0);
        av[0][0] = __builtin_amdgcn_mfma_f32_16x16x32_bf16(a0, v0f, av[0][0], 0, 0, 0);
        av[0][1] = __builtin_amdgcn_mfma_f32_16x16x32_bf16(a0, v1f, av[0][1], 0, 0, 0);
        av[1][0] = __builtin_amdgcn_mfma_f32_16x16x32_bf16(a1, v0f, av[1][0], 0, 0, 0);
        av[1][1] = __builtin_amdgcn_mfma_f32_16x16x32_bf16(a1, v1f, av[1][1], 0, 0, 0);
    }
#pragma unroll
    for (int in = 0; in < 2; in++)
#pragma unroll
        for (int im = 0; im < 2; im++) {
            const int c = m0 + im * 16 + lm;          // output channel
            const int nh = c >> 5, ch = c & 31;
            const int bh = b * 8 + nh;
            const int nbase = n0 + in * 16 + qd * 4;
            {   // K: 4 scattered 2B stores
                const int qdk = ch >> 3, cok = ch & 7;
                const float bs = bk[c];
#pragma unroll
                for (int r = 0; r < 4; r++) {
                    const int n = nbase + r;
                    const int nc = n >> 7, nbk = (n >> 4) & 7, lmk = n & 15;
                    kbt[((bh * 8 + nc) * 512 + nbk * 64 + qdk * 16 + lmk) * 8 + cok] =
                        f2b(ak[in][im][r] + bs);
                }
            }
            {   // V: one ushort4 store
                const float bs = bv[c];
                const int cb = (ch >> 4) & 1, lmv = ch & 15;
                const int nc = nbase >> 7, kc = (nbase >> 5) & 3;
                const int qdv = (nbase >> 3) & 3, co0 = nbase & 7;
                ushort4 r4;
                r4.x = f2b(av[in][im][0] + bs); r4.y = f2b(av[in][im][1] + bs);
                r4.z = f2b(av[in][im][2] + bs); r4.w = f2b(av[in][im][3] + bs);
                *(ushort4*)(vbs + ((bh * 8 + nc) * 512 + (cb * 4 + kc) * 64 + qdv * 16 + lmv) * 8 + co0) = r4;
            }
        }
}

// ---------------------------------------------------------------------------
// Depthwise 5x5 conv, pad 2 (reads q fp32).
// ---------------------------------------------------------------------------
__global__ __launch_bounds__(256) void dwconv(const float* CK q, const float* CK wdw,
                                              const float* CK bdw, float* CK off) {
    const int bx = blockIdx.x;
    const int ch = bx & 63;
    const float* qb = q + bx * HW;
    float w[25];
#pragma unroll
    for (int i = 0; i < 25; i++) w[i] = wdw[ch * 25 + i];
    const float bb = bdw[ch];
    const int t = threadIdx.x;
#pragma unroll
    for (int p = 0; p < 4; p++) {
        int hw = p * 256 + t;
        int ii = hw >> 5, jj = hw & 31;
        float s = bb;
#pragma unroll
        for (int ky = 0; ky < 5; ky++) {
            int y = ii + ky - 2;
            if (y < 0 || y > 31) continue;
#pragma unroll
            for (int kx = 0; kx < 5; kx++) {
                int x = jj + kx - 2;
                if (x < 0 || x > 31) continue;
                s += qb[y * 32 + x] * w[ky * 5 + kx];
            }
        }
        off[bx * HW + hw] = s;
    }
}

// ---------------------------------------------------------------------------
// LayerNorm(64) + exact GELU + projection + tanh + ref -> pos (+outputs 1,2).
// ---------------------------------------------------------------------------
__global__ __launch_bounds__(256) void ln_pos(const float* CK off, const float* CK ln_g,
                                              const float* CK ln_b, const float* CK wpj,
                                              float* CK pos_ws, float* CK out_pos,
                                              float* CK out_ref) {
    const int gid = blockIdx.x * 256 + threadIdx.x;
    const int bg = gid >> 10, hw = gid & 1023;
    const float* ob = off + bg * 64 * HW + hw;
    float s1 = 0.f;
#pragma unroll
    for (int c = 0; c < 64; c++) s1 += ob[c * HW];
    const float mean = s1 * 0.015625f;
    float s2 = 0.f;
#pragma unroll
    for (int c = 0; c < 64; c++) { float d = ob[c * HW] - mean; s2 += d * d; }
    const float rs = rsqrtf(s2 * 0.015625f + 1e-5f);
    float p0 = 0.f, p1 = 0.f;
#pragma unroll
    for (int c = 0; c < 64; c++) {
        float vv = (ob[c * HW] - mean) * rs * ln_g[c] + ln_b[c];
        float gl = 0.5f * vv * (1.f + erff(vv * 0.70710678118654752f));
        p0 += gl * wpj[c];
        p1 += gl * wpj[64 + c];
    }
    const int i = hw >> 5, j = hw & 31;
    const float r0 = (j + 0.5f) * 0.0625f - 1.f;
    const float r1 = (i + 0.5f) * 0.0625f - 1.f;
    const float pos0 = tanhf(p0) * 0.0625f + r0;
    const float pos1 = tanhf(p1) * 0.0625f + r1;
    pos_ws[gid * 2] = pos0;  pos_ws[gid * 2 + 1] = pos1;
    out_pos[gid * 2] = pos0; out_pos[gid * 2 + 1] = pos1;
    out_ref[gid * 2] = r0;   out_ref[gid * 2 + 1] = r1;
}

// ---------------------------------------------------------------------------
// Bilinear sample of x at pos -> xs^T bf16 [b][n][256c].
// ---------------------------------------------------------------------------
__global__ __launch_bounds__(256) void sample_xs(const float* CK x, const float* CK pos_ws,
                                                 ushort* CK xsT) {
    const int gid = blockIdx.x * 256 + threadIdx.x;
    const int bg = gid >> 10, n = gid & 1023;
    const int b = bg >> 2, g = bg & 3;
    const float p0 = pos_ws[gid * 2], p1 = pos_ws[gid * 2 + 1];
    const float gx = (p1 + 1.f) * 15.5f, gy = (p0 + 1.f) * 15.5f;
    const float x0f = floorf(gx), y0f = floorf(gy);
    const float wx1 = gx - x0f, wx0 = 1.f - wx1, wy1 = gy - y0f, wy0 = 1.f - wy1;
    const bool vx0 = (x0f >= 0.f) && (x0f <= 31.f);
    const bool vx1 = (x0f >= -1.f) && (x0f <= 30.f);
    const bool vy0 = (y0f >= 0.f) && (y0f <= 31.f);
    const bool vy1 = (y0f >= -1.f) && (y0f <= 30.f);
    const int xi0 = (int)fminf(fmaxf(x0f, 0.f), 31.f);
    const int xi1 = (int)fminf(fmaxf(x0f + 1.f, 0.f), 31.f);
    const int yi0 = (int)fminf(fmaxf(y0f, 0.f), 31.f);
    const int yi1 = (int)fminf(fmaxf(y0f + 1.f, 0.f), 31.f);
    const float w00 = (vy0 && vx0) ? wy0 * wx0 : 0.f;
    const float w01 = (vy0 && vx1) ? wy0 * wx1 : 0.f;
    const float w10 = (vy1 && vx0) ? wy1 * wx0 : 0.f;
    const float w11 = (vy1 && vx1) ? wy1 * wx1 : 0.f;
    const int o00 = yi0 * 32 + xi0, o01 = yi0 * 32 + xi1;
    const int o10 = yi1 * 32 + xi0, o11 = yi1 * 32 + xi1;
    const float* xb = x + bg * 64 * HW;
    ushort* xo = xsT + b * 262144 + n * 256 + g * 64;
#pragma unroll
    for (int c4 = 0; c4 < 16; c4++) {
        ushort4 r4;
        float vals[4];
#pragma unroll
        for (int j = 0; j < 4; j++) {
            const float* p = xb + (c4 * 4 + j) * HW;
            vals[j] = w00 * p[o00] + w01 * p[o01] + w10 * p[o10] + w11 * p[o11];
        }
        r4.x = f2b(vals[0]); r4.y = f2b(vals[1]); r4.z = f2b(vals[2]); r4.w = f2b(vals[3]);
        *(ushort4*)(xo + c4 * 4) = r4;
    }
}

// ---------------------------------------------------------------------------
// MFMA flash attention, conflict-free LDS layouts.
// grid (16 m-tiles, 32 bh), 256 thr = 4 waves x 16 m.
// K/V staged as straight int4 memcpy (global already fragment-linear);
// fragment reads are lane-linear ds_read_b128 (conflict-free).
// P: D-linear write, 2x b64 read. rpe: zero-ring pad -> 4 taps at
// idx,+1,+65,+66 (fused read2), no clamps. Output: out^T bf16 [b][n][c].
// ---------------------------------------------------------------------------
__global__ __launch_bounds__(256) void attn_mfma(const float* CK q, const ushort* CK kbt,
                                                 const ushort* CK vbs, const float* CK pos_ws,
                                                 const float* CK rpe, ushort* CK aoT) {
    __shared__ __align__(16) float rpe_p[65 * 65];
    __shared__ __align__(16) ushort ksb[4096];
    __shared__ __align__(16) ushort vsb[4096];
    __shared__ __align__(16) ushort Pl[4][2176];   // per-wave 8 blocks x 272
    __shared__ __align__(16) float2 poss2[128];
    const int bh = blockIdx.y;
    const int b = bh >> 3, nh = bh & 7, bg = bh >> 1;
    const int t = threadIdx.x;
    const int w = t >> 6, l = t & 63;
    const int lm = l & 15, qd = l >> 4;

    for (int i = t; i < 65 * 65; i += 256) rpe_p[i] = 0.f;
    __syncthreads();
    {
        const float* rp = rpe + nh * 3969;
        for (int i = t; i < 3969; i += 256) {
            int y = i / 63, x = i - y * 63;
            rpe_p[(y + 1) * 65 + (x + 1)] = rp[i];
        }
    }

    const int m = blockIdx.x * 64 + w * 16 + lm;
    short8 qf;
    {
        union { ushort u[8]; short8 s; } pk;
        const float* qb = q + (b * 256 + nh * 32) * HW + m;
#pragma unroll
        for (int j = 0; j < 8; j++) pk.u[j] = f2b(qb[(qd * 8 + j) * HW]);
        qf = pk.s;
    }
    const float qg0 = ((m & 31) + 0.5f) * 0.0625f - 1.f;
    const float qg1 = ((m >> 5) + 0.5f) * 0.0625f - 1.f;
    const float ax = 31.f + 15.5f * qg1;   // gx = ax - 15.5*pos1
    const float ay = 31.f + 15.5f * qg0;   // gy = ay - 15.5*pos0

    f32x4 oacc0 = {0.f, 0.f, 0.f, 0.f}, oacc1 = {0.f, 0.f, 0.f, 0.f};
    float rmax = -3e38f, rsum = 0.f;
    ushort* PlW = Pl[w];

    for (int nc = 0; nc < 8; nc++) {
        __syncthreads();
        {
            const int4* ksrc = (const int4*)(kbt + (bh * 8 + nc) * 4096);
            int4* kdst = (int4*)ksb;
            kdst[t] = ksrc[t]; kdst[t + 256] = ksrc[t + 256];
            const int4* vsrc = (const int4*)(vbs + (bh * 8 + nc) * 4096);
            int4* vdst = (int4*)vsb;
            vdst[t] = vsrc[t]; vdst[t + 256] = vsrc[t + 256];
            if (t < 128) {
                float2 pp = ((const float2*)pos_ws)[bg * 1024 + nc * 128 + t];
                poss2[t].x = pp.x * 15.5f; poss2[t].y = pp.y * 15.5f;
            }
        }
        __syncthreads();

        // QK^T: S^T[n][m], 8 MFMAs, conflict-free lane-linear reads
        f32x4 sT[8];
#pragma unroll
        for (int nb = 0; nb < 8; nb++) {
            short8 kf = ld8(ksb + (nb * 64 + l) * 8);
            sT[nb] = __builtin_amdgcn_mfma_f32_16x16x32_bf16(kf, qf,
                        (f32x4){0.f, 0.f, 0.f, 0.f}, 0, 0, 0);
        }

        // bias + scale (no clamps needed: zero ring absorbs boundary)
        float cmax = -3e38f;
#pragma unroll
        for (int nb = 0; nb < 8; nb++) {
#pragma unroll
            for (int r = 0; r < 4; r++) {
                const int nl = nb * 16 + qd * 4 + r;
                const float2 ps = poss2[nl];
                const float gx = ax - ps.y;
                const float gy = ay - ps.x;
                const float x0f = floorf(gx), y0f = floorf(gy);
                const float wx1 = gx - x0f, wy1 = gy - y0f;
                const int idx = (int)y0f * 65 + (int)x0f + 66;
                const float t00 = rpe_p[idx],      t01 = rpe_p[idx + 1];
                const float t10 = rpe_p[idx + 65], t11 = rpe_p[idx + 66];
                const float u0 = t00 + wx1 * (t01 - t00);
                const float u1 = t10 + wx1 * (t11 - t10);
                const float bias = u0 + wy1 * (u1 - u0);
                sT[nb][r] = sT[nb][r] * 0.17677669529663687f + bias;
                cmax = fmaxf(cmax, sT[nb][r]);
            }
        }
        cmax = fmaxf(cmax, __shfl_xor(cmax, 16));
        cmax = fmaxf(cmax, __shfl_xor(cmax, 32));
        const float newmax = fmaxf(rmax, cmax);
        const float alpha = __expf(rmax - newmax);
        rmax = newmax;

        // P = exp(s - max) -> bf16, D-linear write (conflict-free)
        float csum = 0.f;
#pragma unroll
        for (int nb = 0; nb < 8; nb++) {
            float e0 = __expf(sT[nb][0] - rmax);
            float e1 = __expf(sT[nb][1] - rmax);
            float e2 = __expf(sT[nb][2] - rmax);
            float e3 = __expf(sT[nb][3] - rmax);
            csum += (e0 + e1) + (e2 + e3);
            uint2 pk;
            pk.x = (unsigned int)f2b(e0) | ((unsigned int)f2b(e1) << 16);
            pk.y = (unsigned int)f2b(e2) | ((unsigned int)f2b(e3) << 16);
            *(uint2*)(PlW + nb * 272 + l * 4) = pk;
        }
        csum += __shfl_xor(csum, 16);
        csum += __shfl_xor(csum, 32);
        rsum = rsum * alpha + csum;
        oacc0 *= alpha;
        oacc1 *= alpha;

        // PV: O^T[c][m] += V[c][n] * P^T[n][m]
#pragma unroll
        for (int kc = 0; kc < 4; kc++) {
            const ushort* pb2 = PlW + (kc * 2 + (qd >> 1)) * 272 + (qd & 1) * 128 + lm * 4;
            union { uint2 u[2]; short8 s; } pfu;
            pfu.u[0] = *(const uint2*)pb2;
            pfu.u[1] = *(const uint2*)(pb2 + 64);
            short8 vf0 = ld8(vsb + (kc * 64 + l) * 8);
            short8 vf1 = ld8(vsb + ((4 + kc) * 64 + l) * 8);
            oacc0 = __builtin_amdgcn_mfma_f32_16x16x32_bf16(vf0, pfu.s, oacc0, 0, 0, 0);
            oacc1 = __builtin_amdgcn_mfma_f32_16x16x32_bf16(vf1, pfu.s, oacc1, 0, 0, 0);
        }
    }

    const float inv = 1.f / rsum;
    ushort* ob = aoT + b * 262144 + m * 256 + nh * 32;
#pragma unroll
    for (int r = 0; r < 4; r++) {
        ob[qd * 4 + r]      = f2b(oacc0[r] * inv);
        ob[16 + qd * 4 + r] = f2b(oacc1[r] * inv);
    }
}

// ---------------------------------------------------------------------------
extern "C" void kernel_launch(void* const* d_in, const int* in_sizes, int n_in,
                              void* d_out, int out_size, void* d_ws, size_t ws_size,
                              hipStream_t stream) {
    (void)in_sizes; (void)n_in; (void)out_size; (void)ws_size;
    const float* x   = (const float*)d_in[0];
    const float* wq  = (const float*)d_in[1];
    const float* bq  = (const float*)d_in[2];
    const float* wdw = (const float*)d_in[3];
    const float* bdw = (const float*)d_in[4];
    const float* lng = (const float*)d_in[5];
    const float* lnb = (const float*)d_in[6];
    const float* wpj = (const float*)d_in[7];
    const float* wk  = (const float*)d_in[8];
    const float* bk  = (const float*)d_in[9];
    const float* wv  = (const float*)d_in[10];
    const float* bv  = (const float*)d_in[11];
    const float* wo  = (const float*)d_in[12];
    const float* bo  = (const float*)d_in[13];
    const float* rpe = (const float*)d_in[14];
    float* outp = (float*)d_out;
    char* base = (char*)d_ws;
    const size_t MB = 1 << 20;

    float*  q_ws   = (float*)(base);                    // 4 MB
    float*  off_ws = (float*)(base + 4 * MB);           // 4 MB
    float*  pos_ws = (float*)(base + 8 * MB);           // 128 KB
    ushort* xT     = (ushort*)(base + 8 * MB + 131072); // 2 MB
    ushort* xsT    = (ushort*)(base + 10 * MB + 131072);
    ushort* kbt    = (ushort*)(base + 12 * MB + 131072);
    ushort* vbs    = (ushort*)(base + 14 * MB + 131072);
    ushort* aoT    = (ushort*)(base + 16 * MB + 131072);
    ushort* wqb    = (ushort*)(base + 18 * MB + 131072);
    ushort* wkb    = (ushort*)(base + 18 * MB + 262144);
    ushort* wvb    = (ushort*)(base + 18 * MB + 393216);
    ushort* wob    = (ushort*)(base + 18 * MB + 524288);

    convw<<<dim3(64, 4), 256, 0, stream>>>(wq, wk, wv, wo, wqb, wkb, wvb, wob);
    convx<<<dim3(32, 4), 256, 0, stream>>>(x, xT);
    gemm_f32<<<dim3(16, 4, 4), 256, 0, stream>>>(xT, wqb, bq, q_ws);
    dwconv<<<1024, 256, 0, stream>>>(q_ws, wdw, bdw, off_ws);
    ln_pos<<<64, 256, 0, stream>>>(off_ws, lng, lnb, wpj, pos_ws,
                                   outp + (1 << 20), outp + (1 << 20) + 32768);
    sample_xs<<<64, 256, 0, stream>>>(x, pos_ws, xsT);
    gemm_kv<<<dim3(16, 4, 4), 256, 0, stream>>>(xsT, wkb, bk, kbt, wvb, bv, vbs);
    attn_mfma<<<dim3(16, 32), 256, 0, stream>>>(q_ws, kbt, vbs, pos_ws, rpe, aoT);
    gemm_f32<<<dim3(16, 4, 4), 256, 0, stream>>>(aoT, wob, bo, outp);
}

// Round 5
// 194.710 us; speedup vs baseline: 2.3598x; 1.1347x over previous
//
#include <hip/hip_runtime.h>
#include <math.h>

#define CK __restrict__

constexpr int CH = 256;
constexpr int HW = 1024;   // 32*32

typedef __attribute__((ext_vector_type(8))) short short8;
typedef __attribute__((ext_vector_type(4))) float f32x4;

__device__ __forceinline__ ushort f2b(float x) {   // fp32 -> bf16 RNE
    union { float f; unsigned int u; } a; a.f = x;
    unsigned int r = (a.u + 0x7FFFu + ((a.u >> 16) & 1u)) >> 16;
    return (ushort)r;
}
__device__ __forceinline__ short8 ld8(const ushort* p) { return *(const short8*)p; }
__device__ __forceinline__ float u2f(unsigned int u) {
    union { unsigned int u; float f; } a; a.u = u; return a.f;
}

// ---------------------------------------------------------------------------
// prep: blocks 0..255 convert the four 256x256 weights to bf16;
//       blocks 256..383 transpose x fp32 [b][c][n] -> xT bf16 [b][n][c].
// ---------------------------------------------------------------------------
__global__ __launch_bounds__(256) void prep(const float* CK w0, const float* CK w1,
                                            const float* CK w2, const float* CK w3,
                                            ushort* CK o0, ushort* CK o1,
                                            ushort* CK o2, ushort* CK o3,
                                            const float* CK x, ushort* CK xT) {
    const int bid = blockIdx.x, t = threadIdx.x;
    if (bid < 256) {
        const float* src; ushort* dst;
        switch (bid >> 6) {
            case 0: src = w0; dst = o0; break;
            case 1: src = w1; dst = o1; break;
            case 2: src = w2; dst = o2; break;
            default: src = w3; dst = o3; break;
        }
        const int i = (bid & 63) * 256 + t;
        float4 v = ((const float4*)src)[i];
        ushort4 r; r.x = f2b(v.x); r.y = f2b(v.y); r.z = f2b(v.z); r.w = f2b(v.w);
        ((ushort4*)dst)[i] = r;
    } else {
        const int b2 = bid - 256;          // 0..127
        const int c8 = b2 & 31, b = b2 >> 5;
        for (int nn = 0; nn < 4; nn++) {
            const int n = nn * 256 + t;
            union { ushort u[8]; short8 s; } pk;
#pragma unroll
            for (int j = 0; j < 8; j++) pk.u[j] = f2b(x[(b * 256 + c8 * 8 + j) * HW + n]);
            *(short8*)(xT + b * 262144 + n * 256 + c8 * 8) = pk.s;
        }
    }
}

// ---------------------------------------------------------------------------
// MFMA GEMM, fp32 out: Y[b][m][n] = sum_c W[m][c] * A^T[n][c] + bias[m].
// grid (16 nt, 4 mt, 4 b), 256 thr = 4 waves, wave = 32m x 32n.  LDS-free.
// ---------------------------------------------------------------------------
__global__ __launch_bounds__(256) void gemm_f32(const ushort* CK AT, const ushort* CK W,
                                                const float* CK bias, float* CK Y) {
    const int b = blockIdx.z;
    const int t = threadIdx.x, w = t >> 6, l = t & 63;
    const int lm = l & 15, qd = l >> 4;
    const int m0 = blockIdx.y * 64 + (w & 1) * 32;
    const int n0 = blockIdx.x * 64 + (w >> 1) * 32;
    const ushort* A = AT + b * 262144 + n0 * 256;
    const ushort* Bm = W + m0 * 256;
    f32x4 acc[2][2] = {};
#pragma unroll
    for (int k0 = 0; k0 < 8; k0++) {
        const int ko = k0 * 32 + qd * 8;
        short8 a0 = ld8(A + lm * 256 + ko);
        short8 a1 = ld8(A + (16 + lm) * 256 + ko);
        short8 b0 = ld8(Bm + lm * 256 + ko);
        short8 b1 = ld8(Bm + (16 + lm) * 256 + ko);
        acc[0][0] = __builtin_amdgcn_mfma_f32_16x16x32_bf16(a0, b0, acc[0][0], 0, 0, 0);
        acc[0][1] = __builtin_amdgcn_mfma_f32_16x16x32_bf16(a0, b1, acc[0][1], 0, 0, 0);
        acc[1][0] = __builtin_amdgcn_mfma_f32_16x16x32_bf16(a1, b0, acc[1][0], 0, 0, 0);
        acc[1][1] = __builtin_amdgcn_mfma_f32_16x16x32_bf16(a1, b1, acc[1][1], 0, 0, 0);
    }
#pragma unroll
    for (int in = 0; in < 2; in++)
#pragma unroll
        for (int im = 0; im < 2; im++) {
            const int m = m0 + im * 16 + lm;
            const float bs = bias[m];
            const int nb_ = n0 + in * 16 + qd * 4;
            float4 r;
            r.x = acc[in][im][0] + bs; r.y = acc[in][im][1] + bs;
            r.z = acc[in][im][2] + bs; r.w = acc[in][im][3] + bs;
            *(float4*)(Y + b * (CH * HW) + m * HW + nb_) = r;
        }
}

// ---------------------------------------------------------------------------
// Fused K+V MFMA GEMM from xs^T; bf16 fragment-linear outputs.
// K uses SWAPPED operand order -> 4 consecutive channels per lane -> ushort4.
// ---------------------------------------------------------------------------
__global__ __launch_bounds__(256) void gemm_kv(const ushort* CK AT,
                                               const ushort* CK Wk, const float* CK bk, ushort* CK kbt,
                                               const ushort* CK Wv, const float* CK bv, ushort* CK vbs) {
    const int b = blockIdx.z;
    const int t = threadIdx.x, w = t >> 6, l = t & 63;
    const int lm = l & 15, qd = l >> 4;
    const int m0 = blockIdx.y * 64 + (w & 1) * 32;
    const int n0 = blockIdx.x * 64 + (w >> 1) * 32;
    const ushort* A = AT + b * 262144 + n0 * 256;
    const ushort* Bk = Wk + m0 * 256;
    const ushort* Bv = Wv + m0 * 256;
    f32x4 akT[2][2] = {}, av[2][2] = {};
#pragma unroll
    for (int k0 = 0; k0 < 8; k0++) {
        const int ko = k0 * 32 + qd * 8;
        short8 a0 = ld8(A + lm * 256 + ko);
        short8 a1 = ld8(A + (16 + lm) * 256 + ko);
        short8 k0f = ld8(Bk + lm * 256 + ko);
        short8 k1f = ld8(Bk + (16 + lm) * 256 + ko);
        short8 v0f = ld8(Bv + lm * 256 + ko);
        short8 v1f = ld8(Bv + (16 + lm) * 256 + ko);
        // K swapped: D rows <- Wk channels, D cols <- xs pixels
        akT[0][0] = __builtin_amdgcn_mfma_f32_16x16x32_bf16(k0f, a0, akT[0][0], 0, 0, 0);
        akT[0][1] = __builtin_amdgcn_mfma_f32_16x16x32_bf16(k0f, a1, akT[0][1], 0, 0, 0);
        akT[1][0] = __builtin_amdgcn_mfma_f32_16x16x32_bf16(k1f, a0, akT[1][0], 0, 0, 0);
        akT[1][1] = __builtin_amdgcn_mfma_f32_16x16x32_bf16(k1f, a1, akT[1][1], 0, 0, 0);
        av[0][0] = __builtin_amdgcn_mfma_f32_16x16x32_bf16(a0, v0f, av[0][0], 0, 0, 0);
        av[0][1] = __builtin_amdgcn_mfma_f32_16x16x32_bf16(a0, v1f, av[0][1], 0, 0, 0);
        av[1][0] = __builtin_amdgcn_mfma_f32_16x16x32_bf16(a1, v0f, av[1][0], 0, 0, 0);
        av[1][1] = __builtin_amdgcn_mfma_f32_16x16x32_bf16(a1, v1f, av[1][1], 0, 0, 0);
    }
#pragma unroll
    for (int im = 0; im < 2; im++)
#pragma unroll
        for (int in = 0; in < 2; in++) {
            {   // K: lane holds K[c0+r][n], c0 = m0+im*16+qd*4, n = n0+in*16+lm
                const int c0 = m0 + im * 16 + qd * 4;
                const int n  = n0 + in * 16 + lm;
                const int nh = c0 >> 5, ch = c0 & 31;
                const int bh = b * 8 + nh;
                const int qdk = ch >> 3, co4 = ch & 7;           // co4 = (qd&1)*4
                const int nc = n >> 7, nbk = (n >> 4) & 7, lmk = n & 15;
                const float4 bks = *(const float4*)(bk + c0);
                ushort4 r4;
                r4.x = f2b(akT[im][in][0] + bks.x);
                r4.y = f2b(akT[im][in][1] + bks.y);
                r4.z = f2b(akT[im][in][2] + bks.z);
                r4.w = f2b(akT[im][in][3] + bks.w);
                *(ushort4*)(kbt + ((bh * 8 + nc) * 512 + nbk * 64 + qdk * 16 + lmk) * 8 + co4) = r4;
            }
            {   // V: lane holds V[c][n0+in*16+qd*4+r], c = m0+im*16+lm
                const int c = m0 + im * 16 + lm;
                const int nh = c >> 5, ch = c & 31;
                const int bh = b * 8 + nh;
                const float bs = bv[c];
                const int cb = (ch >> 4) & 1, lmv = ch & 15;
                const int nbase = n0 + in * 16 + qd * 4;
                const int nc = nbase >> 7, kc = (nbase >> 5) & 3;
                const int qdv = (nbase >> 3) & 3, co0 = nbase & 7;
                ushort4 r4;
                r4.x = f2b(av[in][im][0] + bs); r4.y = f2b(av[in][im][1] + bs);
                r4.z = f2b(av[in][im][2] + bs); r4.w = f2b(av[in][im][3] + bs);
                *(ushort4*)(vbs + ((bh * 8 + nc) * 512 + (cb * 4 + kc) * 64 + qdv * 16 + lmv) * 8 + co0) = r4;
            }
        }
}

// ---------------------------------------------------------------------------
// Depthwise 5x5 conv, pad 2.
// ---------------------------------------------------------------------------
__global__ __launch_bounds__(256) void dwconv(const float* CK q, const float* CK wdw,
                                              const float* CK bdw, float* CK off) {
    const int bx = blockIdx.x;
    const int ch = bx & 63;
    const float* qb = q + bx * HW;
    float w[25];
#pragma unroll
    for (int i = 0; i < 25; i++) w[i] = wdw[ch * 25 + i];
    const float bb = bdw[ch];
    const int t = threadIdx.x;
#pragma unroll
    for (int p = 0; p < 4; p++) {
        int hw = p * 256 + t;
        int ii = hw >> 5, jj = hw & 31;
        float s = bb;
#pragma unroll
        for (int ky = 0; ky < 5; ky++) {
            int y = ii + ky - 2;
            if (y < 0 || y > 31) continue;
#pragma unroll
            for (int kx = 0; kx < 5; kx++) {
                int x = jj + kx - 2;
                if (x < 0 || x > 31) continue;
                s += qb[y * 32 + x] * w[ky * 5 + kx];
            }
        }
        off[bx * HW + hw] = s;
    }
}

// ---------------------------------------------------------------------------
// Fused: LayerNorm(64)+GELU+proj+tanh -> pos (+outputs 1,2), then bilinear
// sample of x at pos -> xs^T bf16.  grid 256 blocks x 64 thr (all CUs).
// ---------------------------------------------------------------------------
__global__ __launch_bounds__(64) void ln_pos_sample(const float* CK off, const float* CK ln_g,
                                                    const float* CK ln_b, const float* CK wpj,
                                                    const float* CK x,
                                                    float* CK pos_ws, float* CK out_pos,
                                                    float* CK out_ref, ushort* CK xsT) {
    const int bg = blockIdx.x >> 4;
    const int n = (blockIdx.x & 15) * 64 + threadIdx.x;
    const int gid = bg * 1024 + n;
    const float* ob = off + bg * 64 * HW + n;
    float s1 = 0.f;
#pragma unroll
    for (int c = 0; c < 64; c++) s1 += ob[c * HW];
    const float mean = s1 * 0.015625f;
    float s2 = 0.f;
#pragma unroll
    for (int c = 0; c < 64; c++) { float d = ob[c * HW] - mean; s2 += d * d; }
    const float rs = rsqrtf(s2 * 0.015625f + 1e-5f);
    float p0a = 0.f, p1a = 0.f;
#pragma unroll
    for (int c = 0; c < 64; c++) {
        float vv = (ob[c * HW] - mean) * rs * ln_g[c] + ln_b[c];
        float gl = 0.5f * vv * (1.f + erff(vv * 0.70710678118654752f));
        p0a += gl * wpj[c];
        p1a += gl * wpj[64 + c];
    }
    const int ii = n >> 5, jj = n & 31;
    const float r0 = (jj + 0.5f) * 0.0625f - 1.f;   // ref ch0 <- column (meshgrid-xy)
    const float r1 = (ii + 0.5f) * 0.0625f - 1.f;   // ref ch1 <- row
    const float pos0 = tanhf(p0a) * 0.0625f + r0;
    const float pos1 = tanhf(p1a) * 0.0625f + r1;
    pos_ws[gid * 2] = pos0;  pos_ws[gid * 2 + 1] = pos1;
    out_pos[gid * 2] = pos0; out_pos[gid * 2 + 1] = pos1;
    out_ref[gid * 2] = r0;   out_ref[gid * 2 + 1] = r1;

    // ---- bilinear sample (reference flips channels: gx<-pos1, gy<-pos0) ----
    const float gx = (pos1 + 1.f) * 15.5f, gy = (pos0 + 1.f) * 15.5f;
    const float x0f = floorf(gx), y0f = floorf(gy);
    const float wx1 = gx - x0f, wx0 = 1.f - wx1, wy1 = gy - y0f, wy0 = 1.f - wy1;
    const bool vx0 = (x0f >= 0.f) && (x0f <= 31.f);
    const bool vx1 = (x0f >= -1.f) && (x0f <= 30.f);
    const bool vy0 = (y0f >= 0.f) && (y0f <= 31.f);
    const bool vy1 = (y0f >= -1.f) && (y0f <= 30.f);
    const int xi0 = (int)fminf(fmaxf(x0f, 0.f), 31.f);
    const int xi1 = (int)fminf(fmaxf(x0f + 1.f, 0.f), 31.f);
    const int yi0 = (int)fminf(fmaxf(y0f, 0.f), 31.f);
    const int yi1 = (int)fminf(fmaxf(y0f + 1.f, 0.f), 31.f);
    const float w00 = (vy0 && vx0) ? wy0 * wx0 : 0.f;
    const float w01 = (vy0 && vx1) ? wy0 * wx1 : 0.f;
    const float w10 = (vy1 && vx0) ? wy1 * wx0 : 0.f;
    const float w11 = (vy1 && vx1) ? wy1 * wx1 : 0.f;
    const int o00 = yi0 * 32 + xi0, o01 = yi0 * 32 + xi1;
    const int o10 = yi1 * 32 + xi0, o11 = yi1 * 32 + xi1;
    const int b = bg >> 2, g = bg & 3;
    const float* xb = x + bg * 64 * HW;
    ushort* xo = xsT + b * 262144 + n * 256 + g * 64;
#pragma unroll
    for (int c4 = 0; c4 < 16; c4++) {
        ushort4 r4;
        float vals[4];
#pragma unroll
        for (int j = 0; j < 4; j++) {
            const float* p = xb + (c4 * 4 + j) * HW;
            vals[j] = w00 * p[o00] + w01 * p[o01] + w10 * p[o10] + w11 * p[o11];
        }
        r4.x = f2b(vals[0]); r4.y = f2b(vals[1]); r4.z = f2b(vals[2]); r4.w = f2b(vals[3]);
        *(ushort4*)(xo + c4 * 4) = r4;
    }
}

// ---------------------------------------------------------------------------
// MFMA flash attention.  Bias gather compressed: rpe as bf16 x-pairs
// (one ds_read_b32 = 2 taps), poss hoisted to 2 ds_read_b128 per 16-n block.
// grid (16 m-tiles, 32 bh), 256 thr = 4 waves x 16 m.
// ---------------------------------------------------------------------------
__global__ __launch_bounds__(256) void attn_mfma(const float* CK q, const ushort* CK kbt,
                                                 const ushort* CK vbs, const float* CK pos_ws,
                                                 const float* CK rpe, ushort* CK aoT) {
    __shared__ __align__(16) unsigned int rpe_pr[65 * 66];   // bf16 pair (x, x+1)
    __shared__ __align__(16) ushort ksb[4096];
    __shared__ __align__(16) ushort vsb[4096];
    __shared__ __align__(16) ushort Pl[4][2176];             // per-wave 8 blk x 272
    __shared__ __align__(16) float2 poss2[128];
    const int bh = blockIdx.y;
    const int b = bh >> 3, nh = bh & 7, bg = bh >> 1;
    const int t = threadIdx.x;
    const int w = t >> 6, l = t & 63;
    const int lm = l & 15, qd = l >> 4;

    {   // build padded pair table: tbl(y,x) = rpe[y-1][x-1] in-range else 0
        const float* rp = rpe + nh * 3969;
        for (int i = t; i < 65 * 66; i += 256) {
            int y = i / 66, x = i - y * 66;
            int yy = y - 1, xx = x - 1;
            bool vy = (yy >= 0) && (yy < 63);
            float a  = (vy && xx >= 0 && xx < 63) ? rp[yy * 63 + xx] : 0.f;
            float bb = (vy && xx + 1 >= 0 && xx + 1 < 63) ? rp[yy * 63 + xx + 1] : 0.f;
            rpe_pr[i] = (unsigned int)f2b(a) | ((unsigned int)f2b(bb) << 16);
        }
    }

    const int m = blockIdx.x * 64 + w * 16 + lm;
    short8 qf;
    {
        union { ushort u[8]; short8 s; } pk;
        const float* qb = q + (b * 256 + nh * 32) * HW + m;
#pragma unroll
        for (int j = 0; j < 8; j++) pk.u[j] = f2b(qb[(qd * 8 + j) * HW]);
        qf = pk.s;
    }
    const float qg0 = ((m & 31) + 0.5f) * 0.0625f - 1.f;
    const float qg1 = ((m >> 5) + 0.5f) * 0.0625f - 1.f;
    const float ax = 31.f + 15.5f * qg1;   // gx = ax - 15.5*pos1
    const float ay = 31.f + 15.5f * qg0;   // gy = ay - 15.5*pos0

    f32x4 oacc0 = {0.f, 0.f, 0.f, 0.f}, oacc1 = {0.f, 0.f, 0.f, 0.f};
    float rmax = -3e38f, rsum = 0.f;
    ushort* PlW = Pl[w];

    for (int nc = 0; nc < 8; nc++) {
        __syncthreads();
        {
            const int4* ksrc = (const int4*)(kbt + (bh * 8 + nc) * 4096);
            int4* kdst = (int4*)ksb;
            kdst[t] = ksrc[t]; kdst[t + 256] = ksrc[t + 256];
            const int4* vsrc = (const int4*)(vbs + (bh * 8 + nc) * 4096);
            int4* vdst = (int4*)vsb;
            vdst[t] = vsrc[t]; vdst[t + 256] = vsrc[t + 256];
            if (t < 128) {
                float2 pp = ((const float2*)pos_ws)[bg * 1024 + nc * 128 + t];
                poss2[t].x = pp.x * 15.5f; poss2[t].y = pp.y * 15.5f;
            }
        }
        __syncthreads();

        // QK^T: S^T[n][m], 8 MFMAs, lane-linear conflict-free reads
        f32x4 sT[8];
#pragma unroll
        for (int nb = 0; nb < 8; nb++) {
            short8 kf = ld8(ksb + (nb * 64 + l) * 8);
            sT[nb] = __builtin_amdgcn_mfma_f32_16x16x32_bf16(kf, qf,
                        (f32x4){0.f, 0.f, 0.f, 0.f}, 0, 0, 0);
        }

        // bias + scale: 2 pair-reads per sample, poss via 2 b128 per nb
        float cmax = -3e38f;
#pragma unroll
        for (int nb = 0; nb < 8; nb++) {
            const float4* pp = (const float4*)&poss2[nb * 16 + qd * 4];
            const float4 pa = pp[0], pb_ = pp[1];
            const float psx[4] = {pa.x, pa.z, pb_.x, pb_.z};
            const float psy[4] = {pa.y, pa.w, pb_.y, pb_.w};
#pragma unroll
            for (int r = 0; r < 4; r++) {
                const float gx = ax - psy[r];
                const float gy = ay - psx[r];
                const float x0f = floorf(gx), y0f = floorf(gy);
                const float wx1 = gx - x0f, wy1 = gy - y0f;
                const int idx = (int)y0f * 66 + (int)x0f + 67;
                const unsigned int pr0 = rpe_pr[idx];
                const unsigned int pr1 = rpe_pr[idx + 66];
                const float t00 = u2f(pr0 << 16), t01 = u2f(pr0 & 0xFFFF0000u);
                const float t10 = u2f(pr1 << 16), t11 = u2f(pr1 & 0xFFFF0000u);
                const float u0 = t00 + wx1 * (t01 - t00);
                const float u1 = t10 + wx1 * (t11 - t10);
                const float bias = u0 + wy1 * (u1 - u0);
                sT[nb][r] = sT[nb][r] * 0.17677669529663687f + bias;
                cmax = fmaxf(cmax, sT[nb][r]);
            }
        }
        cmax = fmaxf(cmax, __shfl_xor(cmax, 16));
        cmax = fmaxf(cmax, __shfl_xor(cmax, 32));
        const float newmax = fmaxf(rmax, cmax);
        const float alpha = __expf(rmax - newmax);
        rmax = newmax;

        // P = exp(s - max) -> bf16, D-linear write (conflict-free)
        float csum = 0.f;
#pragma unroll
        for (int nb = 0; nb < 8; nb++) {
            float e0 = __expf(sT[nb][0] - rmax);
            float e1 = __expf(sT[nb][1] - rmax);
            float e2 = __expf(sT[nb][2] - rmax);
            float e3 = __expf(sT[nb][3] - rmax);
            csum += (e0 + e1) + (e2 + e3);
            uint2 pk;
            pk.x = (unsigned int)f2b(e0) | ((unsigned int)f2b(e1) << 16);
            pk.y = (unsigned int)f2b(e2) | ((unsigned int)f2b(e3) << 16);
            *(uint2*)(PlW + nb * 272 + l * 4) = pk;
        }
        csum += __shfl_xor(csum, 16);
        csum += __shfl_xor(csum, 32);
        rsum = rsum * alpha + csum;
        oacc0 *= alpha;
        oacc1 *= alpha;

        // PV: O^T[c][m] += V[c][n] * P^T[n][m]
#pragma unroll
        for (int kc = 0; kc < 4; kc++) {
            const ushort* pb2 = PlW + (kc * 2 + (qd >> 1)) * 272 + (qd & 1) * 128 + lm * 4;
            union { uint2 u[2]; short8 s; } pfu;
            pfu.u[0] = *(const uint2*)pb2;
            pfu.u[1] = *(const uint2*)(pb2 + 64);
            short8 vf0 = ld8(vsb + (kc * 64 + l) * 8);
            short8 vf1 = ld8(vsb + ((4 + kc) * 64 + l) * 8);
            oacc0 = __builtin_amdgcn_mfma_f32_16x16x32_bf16(vf0, pfu.s, oacc0, 0, 0, 0);
            oacc1 = __builtin_amdgcn_mfma_f32_16x16x32_bf16(vf1, pfu.s, oacc1, 0, 0, 0);
        }
    }

    const float inv = 1.f / rsum;
    ushort* ob = aoT + b * 262144 + m * 256 + nh * 32 + qd * 4;
    ushort4 r04, r14;
    r04.x = f2b(oacc0[0] * inv); r04.y = f2b(oacc0[1] * inv);
    r04.z = f2b(oacc0[2] * inv); r04.w = f2b(oacc0[3] * inv);
    r14.x = f2b(oacc1[0] * inv); r14.y = f2b(oacc1[1] * inv);
    r14.z = f2b(oacc1[2] * inv); r14.w = f2b(oacc1[3] * inv);
    *(ushort4*)ob = r04;
    *(ushort4*)(ob + 16) = r14;
}

// ---------------------------------------------------------------------------
extern "C" void kernel_launch(void* const* d_in, const int* in_sizes, int n_in,
                              void* d_out, int out_size, void* d_ws, size_t ws_size,
                              hipStream_t stream) {
    (void)in_sizes; (void)n_in; (void)out_size; (void)ws_size;
    const float* x   = (const float*)d_in[0];
    const float* wq  = (const float*)d_in[1];
    const float* bq  = (const float*)d_in[2];
    const float* wdw = (const float*)d_in[3];
    const float* bdw = (const float*)d_in[4];
    const float* lng = (const float*)d_in[5];
    const float* lnb = (const float*)d_in[6];
    const float* wpj = (const float*)d_in[7];
    const float* wk  = (const float*)d_in[8];
    const float* bk  = (const float*)d_in[9];
    const float* wv  = (const float*)d_in[10];
    const float* bv  = (const float*)d_in[11];
    const float* wo  = (const float*)d_in[12];
    const float* bo  = (const float*)d_in[13];
    const float* rpe = (const float*)d_in[14];
    float* outp = (float*)d_out;
    char* base = (char*)d_ws;
    const size_t MB = 1 << 20;

    float*  q_ws   = (float*)(base);                    // 4 MB
    float*  off_ws = (float*)(base + 4 * MB);           // 4 MB
    float*  pos_ws = (float*)(base + 8 * MB);           // 128 KB
    ushort* xT     = (ushort*)(base + 8 * MB + 131072); // 2 MB
    ushort* xsT    = (ushort*)(base + 10 * MB + 131072);
    ushort* kbt    = (ushort*)(base + 12 * MB + 131072);
    ushort* vbs    = (ushort*)(base + 14 * MB + 131072);
    ushort* aoT    = (ushort*)(base + 16 * MB + 131072);
    ushort* wqb    = (ushort*)(base + 18 * MB + 131072);
    ushort* wkb    = (ushort*)(base + 18 * MB + 262144);
    ushort* wvb    = (ushort*)(base + 18 * MB + 393216);
    ushort* wob    = (ushort*)(base + 18 * MB + 524288);

    prep<<<384, 256, 0, stream>>>(wq, wk, wv, wo, wqb, wkb, wvb, wob, x, xT);
    gemm_f32<<<dim3(16, 4, 4), 256, 0, stream>>>(xT, wqb, bq, q_ws);
    dwconv<<<1024, 256, 0, stream>>>(q_ws, wdw, bdw, off_ws);
    ln_pos_sample<<<256, 64, 0, stream>>>(off_ws, lng, lnb, wpj, x, pos_ws,
                                          outp + (1 << 20), outp + (1 << 20) + 32768, xsT);
    gemm_kv<<<dim3(16, 4, 4), 256, 0, stream>>>(xsT, wkb, bk, kbt, wvb, bv, vbs);
    attn_mfma<<<dim3(16, 32), 256, 0, stream>>>(q_ws, kbt, vbs, pos_ws, rpe, aoT);
    gemm_f32<<<dim3(16, 4, 4), 256, 0, stream>>>(aoT, wob, bo, outp);
}